// Round 20
// baseline (424.788 us; speedup 1.0000x reference)
//
#include <hip/hip_runtime.h>

#define N_NODES 4096
#define C_DIM   128
#define L_LAYERS 4
#define E_EDGES 131072
#define H_HEADS 4
#define D_HEAD  32
#define NC      (N_NODES * C_DIM)
#define NCu     (N_NODES * C_DIM)
#define P2S     40      // attn P window stride (ushorts)
#define HS_STRIDE 152
#define T2S       264
#define AT_S      136

typedef short bf16x8 __attribute__((ext_vector_type(8)));
typedef float f32x4  __attribute__((ext_vector_type(4)));

__device__ __forceinline__ unsigned short f2bf(float f) {
    unsigned int u = __float_as_uint(f);
    u += 0x7fffu + ((u >> 16) & 1u);
    return (unsigned short)(u >> 16);
}

__device__ __forceinline__ float bf_lo(unsigned int u) { return __uint_as_float(u << 16); }
__device__ __forceinline__ float bf_hi(unsigned int u) { return __uint_as_float(u & 0xffff0000u); }

__device__ __forceinline__ bf16x8 pack8(const float* v) {
    bf16x8 o;
#pragma unroll
    for (int i = 0; i < 8; ++i) o[i] = (short)f2bf(v[i]);
    return o;
}

// ---------------------------------------------------------------------------
// CSR build (once per launch)
// ---------------------------------------------------------------------------
__global__ __launch_bounds__(256) void hist_kernel(const int* __restrict__ ei,
                                                   int* __restrict__ deg) {
    int e = blockIdx.x * 256 + threadIdx.x;
    atomicAdd(&deg[ei[E_EDGES + e]], 1);
}

__global__ __launch_bounds__(256) void scan_kernel(const int* __restrict__ deg,
                                                   int* __restrict__ rowstart,
                                                   int* __restrict__ cursor) {
    __shared__ int ts[256];
    const int tid = threadIdx.x;
    int loc[16];
    int s = 0;
#pragma unroll
    for (int i = 0; i < 16; ++i) { loc[i] = s; s += deg[tid * 16 + i]; }
    ts[tid] = s;
    __syncthreads();
    for (int off = 1; off < 256; off <<= 1) {
        int t = (tid >= off) ? ts[tid - off] : 0;
        __syncthreads();
        if (tid >= off) ts[tid] += t;
        __syncthreads();
    }
    int off0 = ts[tid] - s;
#pragma unroll
    for (int i = 0; i < 16; ++i) {
        int v = off0 + loc[i];
        rowstart[tid * 16 + i] = v;
        cursor[tid * 16 + i] = v;
    }
    if (tid == 255) rowstart[4096] = off0 + s;
}

__global__ __launch_bounds__(256) void fill_kernel(const int* __restrict__ ei,
                                                   int* __restrict__ cursor,
                                                   int* __restrict__ csr_src) {
    int e = blockIdx.x * 256 + threadIdx.x;
    int d = ei[E_EDGES + e];
    int s = ei[e];
    int p = atomicAdd(&cursor[d], 1);
    csr_src[p] = s;
}

// ---------------------------------------------------------------------------
// weight pre-convert fp32 -> bf16
// ---------------------------------------------------------------------------
__global__ __launch_bounds__(256) void wcvt(const float* __restrict__ s0, const float* __restrict__ s1,
                                            const float* __restrict__ s2, const float* __restrict__ s3,
                                            const float* __restrict__ s4, const float* __restrict__ s5,
                                            unsigned short* __restrict__ wbf) {
    int i0 = (blockIdx.x * 256 + threadIdx.x) * 8;
    const float* src; int base;
    if      (i0 < 65536)  { src = s0; base = 0; }
    else if (i0 < 131072) { src = s1; base = 65536; }
    else if (i0 < 327680) { src = s2; base = 131072; }
    else if (i0 < 393216) { src = s3; base = 327680; }
    else if (i0 < 524288) { src = s4; base = 393216; }
    else                  { src = s5; base = 524288; }
    const float* p = src + (i0 - base);
    float t[8];
#pragma unroll
    for (int i = 0; i < 8; ++i) t[i] = p[i];
    *(bf16x8*)(wbf + i0) = pack8(t);
}

// ---------------------------------------------------------------------------
// Fused QKV-GEMM + GIN-gather with deferred BN3 (R17-proven, byte-identical).
// ---------------------------------------------------------------------------
__global__ __launch_bounds__(256, 8) void qkv_gather(const float* __restrict__ xprev,
                                                     const float* __restrict__ st3,
                                                     const float* __restrict__ g3p,
                                                     const float* __restrict__ b3p,
                                                     const unsigned short* __restrict__ Wbf,
                                                     const float* __restrict__ bias,
                                                     unsigned short* __restrict__ Qb,
                                                     unsigned short* __restrict__ Kb,
                                                     unsigned short* __restrict__ VT,
                                                     const int* __restrict__ rowstart,
                                                     const int* __restrict__ csr_src,
                                                     float* __restrict__ ssz,
                                                     unsigned int* __restrict__ hsum) {
    __shared__ float scl2[2][128];
    __shared__ __align__(16) unsigned short at[16 * AT_S];

    const int b = blockIdx.x;
    const int tid = threadIdx.x;
    const float inv_n = 1.f / N_NODES;

    if (b < 1536) {
        const int ct = b % 6, rt = b / 6;
        const int rowbase = rt * 16;

        if (tid < 128) {
            float sc = 1.f, sh = 0.f;
            if (st3) {
                float m = st3[tid] * inv_n;
                float vv = st3[128 + tid] * inv_n - m * m;
                float r = rsqrtf(vv + 1e-5f);
                sc = g3p[tid] * r;
                sh = b3p[tid] - m * sc;
            }
            scl2[0][tid] = sc; scl2[1][tid] = sh;
        }
        __syncthreads();

        {
            const int e0 = tid * 8;
            const int r = e0 >> 7, c = e0 & 127;
            const float* xp = xprev + (size_t)(rowbase + r) * 128 + c;
            float t[8];
#pragma unroll
            for (int i = 0; i < 8; ++i) t[i] = xp[i] * scl2[0][c + i] + scl2[1][c + i];
            *(bf16x8*)(&at[r * AT_S + c]) = pack8(t);
        }
        __syncthreads();

        const int wv = tid >> 6;
        const int lane = tid & 63, lg = lane >> 4, ll = lane & 15;
        const int colbase = ct * 64 + wv * 16;
        const unsigned short* Wp = Wbf + (size_t)(colbase + ll) * 128 + lg * 8;

        f32x4 acc = {0.f, 0.f, 0.f, 0.f};
#pragma unroll
        for (int k = 0; k < 128; k += 32) {
            bf16x8 a = *(const bf16x8*)(&at[ll * AT_S + k + lg * 8]);
            bf16x8 w = *(const bf16x8*)(Wp + k);
            acc = __builtin_amdgcn_mfma_f32_16x16x32_bf16(a, w, acc, 0, 0, 0);
        }

        const float qsc = 0.25506973f;  // (1/sqrt(32)) * log2(e)
        const int col = colbase + ll;
        const float bi = bias[col];
#pragma unroll
        for (int r = 0; r < 4; ++r) {
            const int row = rowbase + lg * 4 + r;
            float v = acc[r] + bi;
            if (col < 128) {
                int hh = col >> 5, d = col & 31;
                Qb[((size_t)hh * N_NODES + row) * D_HEAD + d] = f2bf(v * qsc);
            } else if (col < 256) {
                int c2 = col - 128, hh = c2 >> 5, d = c2 & 31;
                Kb[((size_t)hh * N_NODES + row) * D_HEAD + d] = f2bf(v);
            } else {
                int c2 = col - 256, hh = c2 >> 5, d = c2 & 31;
                VT[((size_t)hh * D_HEAD + d) * N_NODES + row] = f2bf(v);
            }
        }
    } else {
        if (b == 1536) {
            ssz[tid] = 0.f; ssz[256 + tid] = 0.f; ssz[512 + tid] = 0.f;
        }
        const int node = (b - 1536) * 4 + (tid >> 6);
        const int lane = tid & 63;
        const int ch0 = lane * 2, ch1 = ch0 + 1;
        float sc0 = 1.f, sh0 = 0.f, sc1 = 1.f, sh1 = 0.f;
        if (st3) {
            float m0 = st3[ch0] * inv_n;
            float v0 = st3[128 + ch0] * inv_n - m0 * m0;
            float r0 = rsqrtf(v0 + 1e-5f);
            sc0 = g3p[ch0] * r0; sh0 = b3p[ch0] - m0 * sc0;
            float m1 = st3[ch1] * inv_n;
            float v1 = st3[128 + ch1] * inv_n - m1 * m1;
            float r1 = rsqrtf(v1 + 1e-5f);
            sc1 = g3p[ch1] * r1; sh1 = b3p[ch1] - m1 * sc1;
        }
        const int beg = rowstart[node], end = rowstart[node + 1];
        float2 sv = *(const float2*)(xprev + (size_t)node * 128 + ch0);
        float ax = sv.x * sc0 + sh0, ay = sv.y * sc1 + sh1;
        float bx = 0.f, by = 0.f;
        int e = beg;
        for (; e + 4 <= end; e += 4) {
            int s0 = csr_src[e], s1 = csr_src[e + 1], s2 = csr_src[e + 2], s3 = csr_src[e + 3];
            float2 v0 = *(const float2*)(xprev + (size_t)s0 * 128 + ch0);
            float2 v1 = *(const float2*)(xprev + (size_t)s1 * 128 + ch0);
            float2 v2 = *(const float2*)(xprev + (size_t)s2 * 128 + ch0);
            float2 v3 = *(const float2*)(xprev + (size_t)s3 * 128 + ch0);
            ax += (v0.x * sc0 + sh0) + (v1.x * sc0 + sh0);
            ay += (v0.y * sc1 + sh1) + (v1.y * sc1 + sh1);
            bx += (v2.x * sc0 + sh0) + (v3.x * sc0 + sh0);
            by += (v2.y * sc1 + sh1) + (v3.y * sc1 + sh1);
        }
        for (; e < end; ++e) {
            float2 v0 = *(const float2*)(xprev + (size_t)csr_src[e] * 128 + ch0);
            ax += v0.x * sc0 + sh0; ay += v0.y * sc1 + sh1;
        }
        float ox = ax + bx, oy = ay + by;
        hsum[(size_t)node * 64 + lane] = (unsigned int)f2bf(ox) | ((unsigned int)f2bf(oy) << 16);
    }
}

// ---------------------------------------------------------------------------
// Fused attention + GIN-MLP-1, v6: 16-row q-tiles -> grid 1024+256 = 1280
// blocks (5/CU demanded vs 4/CU thread-cap) so CUs stay saturated; R19's
// 512-block grid left ~2 attn blocks/CU. Per-block state halves (1 q-frag,
// 2 accumulators, ~17KB LDS). Same windowed-P math as R19.
// ---------------------------------------------------------------------------
__global__ __launch_bounds__(512, 4) void attn_gin1(const unsigned short* __restrict__ Qb,
                                                    const unsigned short* __restrict__ Kb,
                                                    const unsigned short* __restrict__ VT,
                                                    unsigned short* __restrict__ ob,
                                                    const unsigned short* __restrict__ hsum,
                                                    const unsigned short* __restrict__ W1,
                                                    const float* __restrict__ bias1,
                                                    unsigned short* __restrict__ t1out) {
    __shared__ __align__(16) float Ouns[8][16][33];   // 16896 B (P strips alias this)
    __shared__ float Llp[8][16];                      //   512 B

    const int b   = blockIdx.x;
    const int tid = threadIdx.x;
    const int wv  = tid >> 6;
    const int lane = tid & 63;
    const int lg  = lane >> 4;
    const int ll  = lane & 15;

    if (b >= 1024) {
        // ---- gin1 GEMM branch (unchanged math) ----
        const int rowbase = (b - 1024) * 16;
        const int colbase = wv * 16;
        const unsigned short* Ap = hsum + (size_t)(rowbase + ll) * 128 + lg * 8;
        const unsigned short* Wp = W1 + (size_t)(colbase + ll) * 128 + lg * 8;
        f32x4 acc = {0.f, 0.f, 0.f, 0.f};
#pragma unroll
        for (int k = 0; k < 128; k += 32) {
            bf16x8 a = *(const bf16x8*)(Ap + k);
            bf16x8 w = *(const bf16x8*)(Wp + k);
            acc = __builtin_amdgcn_mfma_f32_16x16x32_bf16(a, w, acc, 0, 0, 0);
        }
        const int col = colbase + ll;
        const float bi = bias1[col];
#pragma unroll
        for (int r = 0; r < 4; ++r) {
            const int row = rowbase + lg * 4 + r;
            float v = fmaxf(acc[r] + bi, 0.f);
            t1out[(size_t)row * 128 + col] = f2bf(v);
        }
        return;
    }

    // ---- attention branch: 16 q-rows per block ----
    const int h   = b >> 8;
    const int q0  = (b & 255) * 16;

    const unsigned short* Qh = Qb + ((size_t)h * N_NODES + q0) * D_HEAD;
    const unsigned short* Kh = Kb + (size_t)h * N_NODES * D_HEAD;
    const unsigned short* Vh = VT + (size_t)h * D_HEAD * N_NODES;

    bf16x8 qf0 = *(const bf16x8*)(Qh + ll * D_HEAD + lg * 8);

    f32x4 o00 = {0.f,0.f,0.f,0.f}, o01 = {0.f,0.f,0.f,0.f};
    float l0[4] = {0.f,0.f,0.f,0.f};

    // per-wave 16 x P2S bf16 P strip aliased into the Ouns storage
    unsigned short* Pw = (unsigned short*)(void*)Ouns + wv * (16 * P2S);
    const int k0 = wv * (N_NODES / 8);
    const unsigned short* Vrow_lo = Vh + (size_t)ll * N_NODES;
    const unsigned short* Vrow_hi = Vh + (size_t)(16 + ll) * N_NODES;

    for (int t = 0; t < (N_NODES / 8) / 128; ++t) {
        const int kt = k0 + t * 128;
#pragma unroll
        for (int j = 0; j < 4; ++j) {
            // QK^T for 32-key window (kc = 2j, 2j+1), exp2, pack into P strip
#pragma unroll
            for (int w = 0; w < 2; ++w) {
                const int kc = 2 * j + w;
                bf16x8 kf = *(const bf16x8*)(Kh + (size_t)(kt + kc * 16 + ll) * D_HEAD + lg * 8);
                f32x4 z = {0.f, 0.f, 0.f, 0.f};
                f32x4 d0 = __builtin_amdgcn_mfma_f32_16x16x32_bf16(qf0, kf, z, 0, 0, 0);
#pragma unroll
                for (int r = 0; r < 4; ++r) {
                    float p0 = exp2f(d0[r]); l0[r] += p0;
                    Pw[(lg * 4 + r) * P2S + w * 16 + ll] = f2bf(p0);
                }
            }
            asm volatile("" ::: "memory");   // same-wave DS ordering fence

            // PV for this window
            const int kb = kt + 32 * j + lg * 8;
            bf16x8 va = *(const bf16x8*)(Vrow_lo + kb);
            bf16x8 vb = *(const bf16x8*)(Vrow_hi + kb);
            bf16x8 pf0 = *(const bf16x8*)(Pw + ll * P2S + lg * 8);
            o00 = __builtin_amdgcn_mfma_f32_16x16x32_bf16(pf0, va, o00, 0, 0, 0);
            o01 = __builtin_amdgcn_mfma_f32_16x16x32_bf16(pf0, vb, o01, 0, 0, 0);
            asm volatile("" ::: "memory");   // keep reads before next window's writes
        }
    }

    // deferred softmax-denominator reduction (16 lanes sharing lg)
#pragma unroll
    for (int r = 0; r < 4; ++r) {
#pragma unroll
        for (int off = 1; off < 16; off <<= 1)
            l0[r] += __shfl_xor(l0[r], off, 64);
    }

    __syncthreads();   // all waves done with P strips; overlay becomes valid

#pragma unroll
    for (int r = 0; r < 4; ++r) {
        Ouns[wv][lg * 4 + r][ll]      = o00[r];
        Ouns[wv][lg * 4 + r][16 + ll] = o01[r];
    }
    if (ll == 0) {
#pragma unroll
        for (int r = 0; r < 4; ++r)
            Llp[wv][lg * 4 + r] = l0[r];
    }
    __syncthreads();

    // merge 8 key-split partials; 512 thr = 16 rows x 32 cols
    {
        const int row = tid >> 5, col = tid & 31;
        float L = 0.f, oa = 0.f;
#pragma unroll
        for (int w = 0; w < 8; ++w) {
            L  += Llp[w][row];
            oa += Ouns[w][row][col];
        }
        ob[(size_t)(q0 + row) * C_DIM + h * D_HEAD + col] = f2bf(oa / L);
    }
}

// ---------------------------------------------------------------------------
// Fused gin2 + aout with deferred-BN3 residual (R17-proven, byte-identical).
// ---------------------------------------------------------------------------
__global__ __launch_bounds__(256, 8) void gemm2x(const unsigned short* __restrict__ A0,
                                                 const unsigned short* __restrict__ W0,
                                                 const float* __restrict__ bias0,
                                                 float* __restrict__ out0,
                                                 float* __restrict__ stats0,
                                                 const unsigned short* __restrict__ A1,
                                                 const unsigned short* __restrict__ W1,
                                                 const float* __restrict__ bias1,
                                                 float* __restrict__ out1,
                                                 float* __restrict__ stats1,
                                                 const float* __restrict__ xprev,
                                                 const float* __restrict__ st3,
                                                 const float* __restrict__ g3p,
                                                 const float* __restrict__ b3p) {
    const int b = blockIdx.x;
    const int which = b >> 9;
    const int bl = b & 511;
    const unsigned short* Abf = which ? A1 : A0;
    const unsigned short* Wbf = which ? W1 : W0;
    const float* bias = which ? bias1 : bias0;
    float* outf  = which ? out1 : out0;
    float* stats = which ? stats1 : stats0;

    const int tid = threadIdx.x;
    const int wv = tid >> 6;
    const int lane = tid & 63, lg = lane >> 4, ll = lane & 15;
    const int rowbase = (bl >> 1) * 16;
    const int colbase = (bl & 1) * 64 + wv * 16;

    const unsigned short* Ap = Abf + (size_t)(rowbase + ll) * 128 + lg * 8;
    const unsigned short* Wp = Wbf + (size_t)(colbase + ll) * 128 + lg * 8;

    f32x4 acc = {0.f, 0.f, 0.f, 0.f};
#pragma unroll
    for (int k = 0; k < 128; k += 32) {
        bf16x8 a = *(const bf16x8*)(Ap + k);
        bf16x8 w = *(const bf16x8*)(Wp + k);
        acc = __builtin_amdgcn_mfma_f32_16x16x32_bf16(a, w, acc, 0, 0, 0);
    }

    const int col = colbase + ll;
    const float bi = bias[col];
    float sc = 1.f, sh = 0.f;
    if (st3) {
        const float inv_n = 1.f / N_NODES;
        float m = st3[col] * inv_n;
        float vv = st3[128 + col] * inv_n - m * m;
        float r = rsqrtf(vv + 1e-5f);
        sc = g3p[col] * r; sh = b3p[col] - m * sc;
    }
    float sv = 0.f, sv2 = 0.f;
#pragma unroll
    for (int r = 0; r < 4; ++r) {
        const int row = rowbase + lg * 4 + r;
        float v = acc[r] + bi + (xprev[(size_t)row * 128 + col] * sc + sh);
        outf[(size_t)row * 128 + col] = v;
        sv += v; sv2 += v * v;
    }
    sv  += __shfl_xor(sv, 16, 64);  sv  += __shfl_xor(sv, 32, 64);
    sv2 += __shfl_xor(sv2, 16, 64); sv2 += __shfl_xor(sv2, 32, 64);
    if (lg == 0) {
        atomicAdd(&stats[col], sv);
        atomicAdd(&stats[128 + col], sv2);
    }
}

// ---------------------------------------------------------------------------
// Fully fused MLP (R16/R17-proven, byte-identical).
// ---------------------------------------------------------------------------
__global__ __launch_bounds__(256) void mlp_fused(const float* __restrict__ g1p,
                                                 const float* __restrict__ a2p,
                                                 const float* __restrict__ st1,
                                                 const float* __restrict__ st2,
                                                 const float* __restrict__ g1v,
                                                 const float* __restrict__ b1v,
                                                 const float* __restrict__ g2v,
                                                 const float* __restrict__ b2v,
                                                 const unsigned short* __restrict__ W1bf,
                                                 const float* __restrict__ bias1,
                                                 const unsigned short* __restrict__ W2bf,
                                                 const float* __restrict__ bias2,
                                                 float* __restrict__ m3out,
                                                 float* __restrict__ stats3) {
    __shared__ float hf[16][132];
    __shared__ __align__(16) unsigned short hs[16 * HS_STRIDE];
    __shared__ __align__(16) unsigned short t2s[16 * T2S];
    __shared__ float scl[4][128];

    const int tid = threadIdx.x;
    const int rowbase = blockIdx.x * 16;
    const float inv_n = 1.f / N_NODES;

    if (tid < 128) {
        const int ch = tid;
        float m1 = st1[ch] * inv_n;
        float v1 = st1[128 + ch] * inv_n - m1 * m1;
        float r1 = rsqrtf(v1 + 1e-5f);
        float sc1 = g1v[ch] * r1;
        scl[0][ch] = sc1;
        scl[1][ch] = b1v[ch] - m1 * sc1;
        float m2 = st2[ch] * inv_n;
        float v2 = st2[128 + ch] * inv_n - m2 * m2;
        float r2 = rsqrtf(v2 + 1e-5f);
        float sc2 = g2v[ch] * r2;
        scl[2][ch] = sc2;
        scl[3][ch] = b2v[ch] - m2 * sc2;
    }
    __syncthreads();

#pragma unroll
    for (int j = tid; j < 512; j += 256) {
        const int r = j >> 5, cq = (j & 31) * 4;
        float4 v1 = *(const float4*)(g1p + (size_t)(rowbase + r) * 128 + cq);
        float4 v2 = *(const float4*)(a2p + (size_t)(rowbase + r) * 128 + cq);
        float h0 = v1.x * scl[0][cq]     + scl[1][cq]     + v2.x * scl[2][cq]     + scl[3][cq];
        float h1 = v1.y * scl[0][cq + 1] + scl[1][cq + 1] + v2.y * scl[2][cq + 1] + scl[3][cq + 1];
        float h2 = v1.z * scl[0][cq + 2] + scl[1][cq + 2] + v2.z * scl[2][cq + 2] + scl[3][cq + 2];
        float h3 = v1.w * scl[0][cq + 3] + scl[1][cq + 3] + v2.w * scl[2][cq + 3] + scl[3][cq + 3];
        hf[r][cq] = h0; hf[r][cq + 1] = h1; hf[r][cq + 2] = h2; hf[r][cq + 3] = h3;
        ushort4 u;
        u.x = f2bf(h0); u.y = f2bf(h1); u.z = f2bf(h2); u.w = f2bf(h3);
        *(ushort4*)(&hs[r * HS_STRIDE + cq]) = u;
    }
    __syncthreads();

    const int wv = tid >> 6;
    const int lane = tid & 63, lg = lane >> 4, ll = lane & 15;

#pragma unroll
    for (int ct = 0; ct < 4; ++ct) {
        const int colbase = wv * 16 + ct * 64;
        const unsigned short* Wp = W1bf + (size_t)(colbase + ll) * 128 + lg * 8;
        f32x4 acc = {0.f, 0.f, 0.f, 0.f};
#pragma unroll
        for (int k = 0; k < 128; k += 32) {
            bf16x8 a = *(const bf16x8*)(&hs[ll * HS_STRIDE + k + lg * 8]);
            bf16x8 w = *(const bf16x8*)(Wp + k);
            acc = __builtin_amdgcn_mfma_f32_16x16x32_bf16(a, w, acc, 0, 0, 0);
        }
        const int col = colbase + ll;
        const float bi = bias1[col];
#pragma unroll
        for (int r = 0; r < 4; ++r) {
            float v = fmaxf(acc[r] + bi, 0.f);
            t2s[(lg * 4 + r) * T2S + col] = f2bf(v);
        }
    }
    __syncthreads();

#pragma unroll
    for (int p = 0; p < 2; ++p) {
        const int colbase = p * 64 + wv * 16;
        const unsigned short* Wp = W2bf + (size_t)(colbase + ll) * 256 + lg * 8;
        f32x4 acc = {0.f, 0.f, 0.f, 0.f};
#pragma unroll
        for (int k = 0; k < 256; k += 32) {
            bf16x8 a = *(const bf16x8*)(&t2s[ll * T2S + k + lg * 8]);
            bf16x8 w = *(const bf16x8*)(Wp + k);
            acc = __builtin_amdgcn_mfma_f32_16x16x32_bf16(a, w, acc, 0, 0, 0);
        }
        const int col = colbase + ll;
        const float bi = bias2[col];
        float sv = 0.f, sv2 = 0.f;
#pragma unroll
        for (int r = 0; r < 4; ++r) {
            const int row = lg * 4 + r;
            float v = acc[r] + bi + hf[row][col];
            m3out[(size_t)(rowbase + row) * 128 + col] = v;
            sv += v; sv2 += v * v;
        }
        sv  += __shfl_xor(sv, 16, 64);  sv  += __shfl_xor(sv, 32, 64);
        sv2 += __shfl_xor(sv2, 16, 64); sv2 += __shfl_xor(sv2, 32, 64);
        if (lg == 0) {
            atomicAdd(&stats3[col], sv);
            atomicAdd(&stats3[128 + col], sv2);
        }
    }
}

// ---------------------------------------------------------------------------
// Fused head MLP with deferred BN3 (R17-proven, byte-identical).
// ---------------------------------------------------------------------------
__global__ __launch_bounds__(256) void head_fused(const float* __restrict__ m3p,
                                                  const float* __restrict__ st3,
                                                  const float* __restrict__ g3p,
                                                  const float* __restrict__ b3p,
                                                  const float* __restrict__ w1,
                                                  const float* __restrict__ b1,
                                                  const float* __restrict__ w2,
                                                  const float* __restrict__ b2,
                                                  const float* __restrict__ w3,
                                                  const float* __restrict__ b3,
                                                  float* __restrict__ out) {
    __shared__ __align__(16) float xs[8][128];
    __shared__ __align__(16) float hs2[8][64];
    __shared__ float scl2[2][128];
    const int tid = threadIdx.x;
    const int n = tid >> 5;
    const int g = tid & 31;
    const int node0 = blockIdx.x * 8;
    const float inv_n = 1.f / N_NODES;

    if (tid < 128) {
        float m = st3[tid] * inv_n;
        float vv = st3[128 + tid] * inv_n - m * m;
        float r = rsqrtf(vv + 1e-5f);
        float sc = g3p[tid] * r;
        scl2[0][tid] = sc;
        scl2[1][tid] = b3p[tid] - m * sc;
    }
    __syncthreads();

    {
        const int e0 = tid * 4;
        const int r = e0 >> 7, c = e0 & 127;
        float4 v = *(const float4*)(m3p + (size_t)(node0 + r) * 128 + c);
        xs[r][c]     = v.x * scl2[0][c]     + scl2[1][c];
        xs[r][c + 1] = v.y * scl2[0][c + 1] + scl2[1][c + 1];
        xs[r][c + 2] = v.z * scl2[0][c + 2] + scl2[1][c + 2];
        xs[r][c + 3] = v.w * scl2[0][c + 3] + scl2[1][c + 3];
    }
    __syncthreads();

    {
        float acc0 = b1[g], acc1 = b1[g + 32];
        const float* wa = w1 + (size_t)g * 128;
        const float* wb = w1 + (size_t)(g + 32) * 128;
#pragma unroll 8
        for (int k = 0; k < 128; k += 4) {
            float4 xv = *(const float4*)(&xs[n][k]);
            float4 va = *(const float4*)(wa + k);
            float4 vb = *(const float4*)(wb + k);
            acc0 += xv.x * va.x + xv.y * va.y + xv.z * va.z + xv.w * va.w;
            acc1 += xv.x * vb.x + xv.y * vb.y + xv.z * vb.z + xv.w * vb.w;
        }
        hs2[n][g]      = fmaxf(acc0, 0.f);
        hs2[n][g + 32] = fmaxf(acc1, 0.f);
    }
    __syncthreads();

    {
        float acc = b2[g];
        const float* wr = w2 + (size_t)g * 64;
#pragma unroll 8
        for (int k = 0; k < 64; k += 4) {
            float4 hv = *(const float4*)(&hs2[n][k]);
            float4 wv = *(const float4*)(wr + k);
            acc += hv.x * wv.x + hv.y * wv.y + hv.z * wv.z + hv.w * wv.w;
        }
        float t = fmaxf(acc, 0.f) * w3[g];
#pragma unroll
        for (int off = 1; off < 32; off <<= 1) t += __shfl_xor(t, off, 64);
        if (g == 0) out[node0 + n] = t + b3[0];
    }
}

// ---------------------------------------------------------------------------
extern "C" void kernel_launch(void* const* d_in, const int* in_sizes, int n_in,
                              void* d_out, int out_size, void* d_ws, size_t ws_size,
                              hipStream_t stream) {
    (void)in_sizes; (void)n_in; (void)out_size; (void)ws_size;
    const float* x_in   = (const float*)d_in[0];
    const int*   ei     = (const int*)d_in[1];
    const float* gin_w1 = (const float*)d_in[2];
    const float* gin_b1 = (const float*)d_in[3];
    const float* gin_w2 = (const float*)d_in[4];
    const float* gin_b2 = (const float*)d_in[5];
    const float* ain_w  = (const float*)d_in[6];
    const float* ain_b  = (const float*)d_in[7];
    const float* aout_w = (const float*)d_in[8];
    const float* aout_b = (const float*)d_in[9];
    const float* n1_g   = (const float*)d_in[10];
    const float* n1_b   = (const float*)d_in[11];
    const float* n2_g   = (const float*)d_in[12];
    const float* n2_b   = (const float*)d_in[13];
    const float* n3_g   = (const float*)d_in[14];
    const float* n3_b   = (const float*)d_in[15];
    const float* mlp_w1 = (const float*)d_in[16];
    const float* mlp_b1 = (const float*)d_in[17];
    const float* mlp_w2 = (const float*)d_in[18];
    const float* mlp_b2 = (const float*)d_in[19];
    const float* h_w1   = (const float*)d_in[20];
    const float* h_b1   = (const float*)d_in[21];
    const float* h_w2   = (const float*)d_in[22];
    const float* h_b2   = (const float*)d_in[23];
    const float* h_w3   = (const float*)d_in[24];
    const float* h_b3   = (const float*)d_in[25];

    float* f = (float*)d_ws;
    float* g1   = f;                   // c0
    float* a2   = f + 1 * (size_t)NC;  // c1 (hsum ushort overlay during steps 1-2)
    float* t1ch = f + 2 * (size_t)NC;  // c2 (t1_bf ushort overlay)
    float* m3   = f + 3 * (size_t)NC;  // c3 (dedicated; persists into next layer)
    unsigned short* R1  = (unsigned short*)(f + 4 * (size_t)NC);  // 3 NCu
    unsigned short* Qb      = R1;
    unsigned short* Kb      = R1 + (size_t)NCu;
    unsigned short* VT      = R1 + 2 * (size_t)NCu;
    unsigned short* R2      = R1 + 3 * (size_t)NCu;  // 1 NCu
    unsigned short* ao_bf   = R2;                    // attn out
    unsigned short* hsum_bf = (unsigned short*)a2;   // gather out (c1 overlay)
    unsigned short* t1_bf   = (unsigned short*)t1ch; // gin1 out (c2 overlay)
    unsigned short* wbf     = R2 + (size_t)NCu;
    float* ssA    = (float*)(wbf + 655360);   // 768 raw sums (parity 0)
    float* ssB    = ssA + 768;                // 768 raw sums (parity 1)
    int* ibase    = (int*)(ssB + 768);
    int* deg      = ibase;
    int* rowstart = ibase + 4096;
    int* cursor   = ibase + 4096 + 4098;
    int* csr_src  = ibase + 4096 + 4098 + 4096;

    const int OG1 = 0, OG2 = 65536, OAI = 131072, OAO = 327680, OM1 = 393216, OM2 = 524288;

    hipMemsetAsync(deg, 0, 4096 * sizeof(int), stream);
    hist_kernel<<<E_EDGES / 256, 256, 0, stream>>>(ei, deg);
    scan_kernel<<<1, 256, 0, stream>>>(deg, rowstart, cursor);
    fill_kernel<<<E_EDGES / 256, 256, 0, stream>>>(ei, cursor, csr_src);
    wcvt<<<320, 256, 0, stream>>>(gin_w1, gin_w2, ain_w, aout_w, mlp_w1, mlp_w2, wbf);

    for (int i = 0; i < L_LAYERS; ++i) {
        const float* xprev = (i == 0) ? x_in : m3;
        const float* st3p  = (i == 0) ? nullptr : ((i & 1) ? ssA : ssB) + 512;
        const float* g3p   = (i == 0) ? nullptr : n3_g + (size_t)(i - 1) * C_DIM;
        const float* b3p   = (i == 0) ? nullptr : n3_b + (size_t)(i - 1) * C_DIM;
        float* ss_cur = (i & 1) ? ssB : ssA;
        const float* gb1 = gin_b1 + (size_t)i * C_DIM;
        const float* gb2 = gin_b2 + (size_t)i * C_DIM;
        const float* aib = ain_b + (size_t)i * 3 * C_DIM;
        const float* aob = aout_b + (size_t)i * C_DIM;
        const float* mb1 = mlp_b1 + (size_t)i * 2 * C_DIM;
        const float* mb2 = mlp_b2 + (size_t)i * C_DIM;

        // 1) fused QKV GEMM + GIN gather, deferred BN3 from (xprev, st3p)
        qkv_gather<<<2560, 256, 0, stream>>>(xprev, st3p, g3p, b3p,
                                             wbf + OAI + (size_t)i * 49152, aib,
                                             Qb, Kb, VT, rowstart, csr_src,
                                             ss_cur, (unsigned int*)hsum_bf);
        // 2) fused attention + gin1 (v6: 16-row q-tiles, grid 1280)
        attn_gin1<<<1280, 512, 0, stream>>>(Qb, Kb, VT, ao_bf,
                                            hsum_bf, wbf + OG1 + (size_t)i * 16384, gb1, t1_bf);
        // 3) fused gin2 + aout (deferred-BN3 residual)
        gemm2x<<<1024, 256, 0, stream>>>(t1_bf, wbf + OG2 + (size_t)i * 16384, gb2, g1, ss_cur,
                                         ao_bf, wbf + OAO + (size_t)i * 16384, aob, a2, ss_cur + 256,
                                         xprev, st3p, g3p, b3p);
        // 4) fully fused MLP -> m3 (c3) + BN3 stats
        mlp_fused<<<256, 256, 0, stream>>>(g1, a2, ss_cur, ss_cur + 256,
                                           n1_g + (size_t)i * C_DIM, n1_b + (size_t)i * C_DIM,
                                           n2_g + (size_t)i * C_DIM, n2_b + (size_t)i * C_DIM,
                                           wbf + OM1 + (size_t)i * 32768, mb1,
                                           wbf + OM2 + (size_t)i * 32768, mb2,
                                           m3, ss_cur + 512);
    }

    // head: x = bn3(m3 of layer 3), scales from ssB+512 (layer-3 parity)
    head_fused<<<N_NODES / 8, 256, 0, stream>>>(m3, ssB + 512,
                                                n3_g + 3 * (size_t)C_DIM, n3_b + 3 * (size_t)C_DIM,
                                                h_w1, h_b1, h_w2, h_b2, h_w3, h_b3,
                                                (float*)d_out);
}

// Round 21
// 354.076 us; speedup vs baseline: 1.1997x; 1.1997x over previous
//
#include <hip/hip_runtime.h>

#define N_NODES 4096
#define C_DIM   128
#define L_LAYERS 4
#define E_EDGES 131072
#define H_HEADS 4
#define D_HEAD  32
#define NC      (N_NODES * C_DIM)
#define NCu     (N_NODES * C_DIM)
#define P2S     40      // attn P window stride (ushorts): 80B rows, 16B-aligned
#define HS_STRIDE 152
#define T2S       264
#define AT_S      136

typedef short bf16x8 __attribute__((ext_vector_type(8)));
typedef float f32x4  __attribute__((ext_vector_type(4)));

__device__ __forceinline__ unsigned short f2bf(float f) {
    unsigned int u = __float_as_uint(f);
    u += 0x7fffu + ((u >> 16) & 1u);
    return (unsigned short)(u >> 16);
}

__device__ __forceinline__ float bf_lo(unsigned int u) { return __uint_as_float(u << 16); }
__device__ __forceinline__ float bf_hi(unsigned int u) { return __uint_as_float(u & 0xffff0000u); }

__device__ __forceinline__ bf16x8 pack8(const float* v) {
    bf16x8 o;
#pragma unroll
    for (int i = 0; i < 8; ++i) o[i] = (short)f2bf(v[i]);
    return o;
}

// ---------------------------------------------------------------------------
// CSR build (once per launch)
// ---------------------------------------------------------------------------
__global__ __launch_bounds__(256) void hist_kernel(const int* __restrict__ ei,
                                                   int* __restrict__ deg) {
    int e = blockIdx.x * 256 + threadIdx.x;
    atomicAdd(&deg[ei[E_EDGES + e]], 1);
}

__global__ __launch_bounds__(256) void scan_kernel(const int* __restrict__ deg,
                                                   int* __restrict__ rowstart,
                                                   int* __restrict__ cursor) {
    __shared__ int ts[256];
    const int tid = threadIdx.x;
    int loc[16];
    int s = 0;
#pragma unroll
    for (int i = 0; i < 16; ++i) { loc[i] = s; s += deg[tid * 16 + i]; }
    ts[tid] = s;
    __syncthreads();
    for (int off = 1; off < 256; off <<= 1) {
        int t = (tid >= off) ? ts[tid - off] : 0;
        __syncthreads();
        if (tid >= off) ts[tid] += t;
        __syncthreads();
    }
    int off0 = ts[tid] - s;
#pragma unroll
    for (int i = 0; i < 16; ++i) {
        int v = off0 + loc[i];
        rowstart[tid * 16 + i] = v;
        cursor[tid * 16 + i] = v;
    }
    if (tid == 255) rowstart[4096] = off0 + s;
}

__global__ __launch_bounds__(256) void fill_kernel(const int* __restrict__ ei,
                                                   int* __restrict__ cursor,
                                                   int* __restrict__ csr_src) {
    int e = blockIdx.x * 256 + threadIdx.x;
    int d = ei[E_EDGES + e];
    int s = ei[e];
    int p = atomicAdd(&cursor[d], 1);
    csr_src[p] = s;
}

// ---------------------------------------------------------------------------
// weight pre-convert fp32 -> bf16
// ---------------------------------------------------------------------------
__global__ __launch_bounds__(256) void wcvt(const float* __restrict__ s0, const float* __restrict__ s1,
                                            const float* __restrict__ s2, const float* __restrict__ s3,
                                            const float* __restrict__ s4, const float* __restrict__ s5,
                                            unsigned short* __restrict__ wbf) {
    int i0 = (blockIdx.x * 256 + threadIdx.x) * 8;
    const float* src; int base;
    if      (i0 < 65536)  { src = s0; base = 0; }
    else if (i0 < 131072) { src = s1; base = 65536; }
    else if (i0 < 327680) { src = s2; base = 131072; }
    else if (i0 < 393216) { src = s3; base = 327680; }
    else if (i0 < 524288) { src = s4; base = 393216; }
    else                  { src = s5; base = 524288; }
    const float* p = src + (i0 - base);
    float t[8];
#pragma unroll
    for (int i = 0; i < 8; ++i) t[i] = p[i];
    *(bf16x8*)(wbf + i0) = pack8(t);
}

// ---------------------------------------------------------------------------
// Fused QKV-GEMM + GIN-gather with deferred BN3 (R17-proven, byte-identical).
// ---------------------------------------------------------------------------
__global__ __launch_bounds__(256, 8) void qkv_gather(const float* __restrict__ xprev,
                                                     const float* __restrict__ st3,
                                                     const float* __restrict__ g3p,
                                                     const float* __restrict__ b3p,
                                                     const unsigned short* __restrict__ Wbf,
                                                     const float* __restrict__ bias,
                                                     unsigned short* __restrict__ Qb,
                                                     unsigned short* __restrict__ Kb,
                                                     unsigned short* __restrict__ VT,
                                                     const int* __restrict__ rowstart,
                                                     const int* __restrict__ csr_src,
                                                     float* __restrict__ ssz,
                                                     unsigned int* __restrict__ hsum) {
    __shared__ float scl2[2][128];
    __shared__ __align__(16) unsigned short at[16 * AT_S];

    const int b = blockIdx.x;
    const int tid = threadIdx.x;
    const float inv_n = 1.f / N_NODES;

    if (b < 1536) {
        const int ct = b % 6, rt = b / 6;
        const int rowbase = rt * 16;

        if (tid < 128) {
            float sc = 1.f, sh = 0.f;
            if (st3) {
                float m = st3[tid] * inv_n;
                float vv = st3[128 + tid] * inv_n - m * m;
                float r = rsqrtf(vv + 1e-5f);
                sc = g3p[tid] * r;
                sh = b3p[tid] - m * sc;
            }
            scl2[0][tid] = sc; scl2[1][tid] = sh;
        }
        __syncthreads();

        {
            const int e0 = tid * 8;
            const int r = e0 >> 7, c = e0 & 127;
            const float* xp = xprev + (size_t)(rowbase + r) * 128 + c;
            float t[8];
#pragma unroll
            for (int i = 0; i < 8; ++i) t[i] = xp[i] * scl2[0][c + i] + scl2[1][c + i];
            *(bf16x8*)(&at[r * AT_S + c]) = pack8(t);
        }
        __syncthreads();

        const int wv = tid >> 6;
        const int lane = tid & 63, lg = lane >> 4, ll = lane & 15;
        const int colbase = ct * 64 + wv * 16;
        const unsigned short* Wp = Wbf + (size_t)(colbase + ll) * 128 + lg * 8;

        f32x4 acc = {0.f, 0.f, 0.f, 0.f};
#pragma unroll
        for (int k = 0; k < 128; k += 32) {
            bf16x8 a = *(const bf16x8*)(&at[ll * AT_S + k + lg * 8]);
            bf16x8 w = *(const bf16x8*)(Wp + k);
            acc = __builtin_amdgcn_mfma_f32_16x16x32_bf16(a, w, acc, 0, 0, 0);
        }

        const float qsc = 0.25506973f;  // (1/sqrt(32)) * log2(e)
        const int col = colbase + ll;
        const float bi = bias[col];
#pragma unroll
        for (int r = 0; r < 4; ++r) {
            const int row = rowbase + lg * 4 + r;
            float v = acc[r] + bi;
            if (col < 128) {
                int hh = col >> 5, d = col & 31;
                Qb[((size_t)hh * N_NODES + row) * D_HEAD + d] = f2bf(v * qsc);
            } else if (col < 256) {
                int c2 = col - 128, hh = c2 >> 5, d = c2 & 31;
                Kb[((size_t)hh * N_NODES + row) * D_HEAD + d] = f2bf(v);
            } else {
                int c2 = col - 256, hh = c2 >> 5, d = c2 & 31;
                VT[((size_t)hh * D_HEAD + d) * N_NODES + row] = f2bf(v);
            }
        }
    } else {
        if (b == 1536) {
            ssz[tid] = 0.f; ssz[256 + tid] = 0.f; ssz[512 + tid] = 0.f;
        }
        const int node = (b - 1536) * 4 + (tid >> 6);
        const int lane = tid & 63;
        const int ch0 = lane * 2, ch1 = ch0 + 1;
        float sc0 = 1.f, sh0 = 0.f, sc1 = 1.f, sh1 = 0.f;
        if (st3) {
            float m0 = st3[ch0] * inv_n;
            float v0 = st3[128 + ch0] * inv_n - m0 * m0;
            float r0 = rsqrtf(v0 + 1e-5f);
            sc0 = g3p[ch0] * r0; sh0 = b3p[ch0] - m0 * sc0;
            float m1 = st3[ch1] * inv_n;
            float v1 = st3[128 + ch1] * inv_n - m1 * m1;
            float r1 = rsqrtf(v1 + 1e-5f);
            sc1 = g3p[ch1] * r1; sh1 = b3p[ch1] - m1 * sc1;
        }
        const int beg = rowstart[node], end = rowstart[node + 1];
        float2 sv = *(const float2*)(xprev + (size_t)node * 128 + ch0);
        float ax = sv.x * sc0 + sh0, ay = sv.y * sc1 + sh1;
        float bx = 0.f, by = 0.f;
        int e = beg;
        for (; e + 4 <= end; e += 4) {
            int s0 = csr_src[e], s1 = csr_src[e + 1], s2 = csr_src[e + 2], s3 = csr_src[e + 3];
            float2 v0 = *(const float2*)(xprev + (size_t)s0 * 128 + ch0);
            float2 v1 = *(const float2*)(xprev + (size_t)s1 * 128 + ch0);
            float2 v2 = *(const float2*)(xprev + (size_t)s2 * 128 + ch0);
            float2 v3 = *(const float2*)(xprev + (size_t)s3 * 128 + ch0);
            ax += (v0.x * sc0 + sh0) + (v1.x * sc0 + sh0);
            ay += (v0.y * sc1 + sh1) + (v1.y * sc1 + sh1);
            bx += (v2.x * sc0 + sh0) + (v3.x * sc0 + sh0);
            by += (v2.y * sc1 + sh1) + (v3.y * sc1 + sh1);
        }
        for (; e < end; ++e) {
            float2 v0 = *(const float2*)(xprev + (size_t)csr_src[e] * 128 + ch0);
            ax += v0.x * sc0 + sh0; ay += v0.y * sc1 + sh1;
        }
        float ox = ax + bx, oy = ay + by;
        hsum[(size_t)node * 64 + lane] = (unsigned int)f2bf(ox) | ((unsigned int)f2bf(oy) << 16);
    }
}

// ---------------------------------------------------------------------------
// Fused attention + GIN-MLP-1, v5b (R19 session-best, byte-identical):
// 32-row q-tiles, 2 q-frags/wave (K-frag reuse x2), 32-key P windows
// (34.8KB LDS), natural VGPR budget (launch_bounds 512,4).
// R18 (VGPR cap 8/SIMD) spilled: 145MB FETCH. R20 (16-row tiles) halved
// K-reuse: 54.6us. This configuration is the measured optimum.
// ---------------------------------------------------------------------------
__global__ __launch_bounds__(512, 4) void attn_gin1(const unsigned short* __restrict__ Qb,
                                                    const unsigned short* __restrict__ Kb,
                                                    const unsigned short* __restrict__ VT,
                                                    unsigned short* __restrict__ ob,
                                                    const unsigned short* __restrict__ hsum,
                                                    const unsigned short* __restrict__ W1,
                                                    const float* __restrict__ bias1,
                                                    unsigned short* __restrict__ t1out) {
    __shared__ __align__(16) float Ouns[8][32][33];   // 33792 B (P strips alias this)
    __shared__ float Llp[8][32];                      //  1024 B

    const int b   = blockIdx.x;
    const int tid = threadIdx.x;
    const int wv  = tid >> 6;
    const int lane = tid & 63;
    const int lg  = lane >> 4;
    const int ll  = lane & 15;

    if (b >= 512) {
        // ---- gin1 GEMM branch ----
        const int rowbase = (b - 512) * 16;
        const int colbase = wv * 16;
        const unsigned short* Ap = hsum + (size_t)(rowbase + ll) * 128 + lg * 8;
        const unsigned short* Wp = W1 + (size_t)(colbase + ll) * 128 + lg * 8;
        f32x4 acc = {0.f, 0.f, 0.f, 0.f};
#pragma unroll
        for (int k = 0; k < 128; k += 32) {
            bf16x8 a = *(const bf16x8*)(Ap + k);
            bf16x8 w = *(const bf16x8*)(Wp + k);
            acc = __builtin_amdgcn_mfma_f32_16x16x32_bf16(a, w, acc, 0, 0, 0);
        }
        const int col = colbase + ll;
        const float bi = bias1[col];
#pragma unroll
        for (int r = 0; r < 4; ++r) {
            const int row = rowbase + lg * 4 + r;
            float v = fmaxf(acc[r] + bi, 0.f);
            t1out[(size_t)row * 128 + col] = f2bf(v);
        }
        return;
    }

    // ---- attention branch ----
    const int h   = b >> 7;
    const int q0  = (b & 127) * 32;

    const unsigned short* Qh = Qb + ((size_t)h * N_NODES + q0) * D_HEAD;
    const unsigned short* Kh = Kb + (size_t)h * N_NODES * D_HEAD;
    const unsigned short* Vh = VT + (size_t)h * D_HEAD * N_NODES;

    bf16x8 qf0 = *(const bf16x8*)(Qh + ll * D_HEAD + lg * 8);
    bf16x8 qf1 = *(const bf16x8*)(Qh + (16 + ll) * D_HEAD + lg * 8);

    f32x4 o00 = {0.f,0.f,0.f,0.f}, o01 = {0.f,0.f,0.f,0.f};
    f32x4 o10 = {0.f,0.f,0.f,0.f}, o11 = {0.f,0.f,0.f,0.f};
    float l0[4] = {0.f,0.f,0.f,0.f}, l1[4] = {0.f,0.f,0.f,0.f};

    // per-wave 32x(32+8) bf16 P strip aliased into the Ouns storage
    unsigned short* Pw = (unsigned short*)(void*)Ouns + wv * (32 * P2S);
    const int k0 = wv * (N_NODES / 8);
    const unsigned short* Vrow_lo = Vh + (size_t)ll * N_NODES;
    const unsigned short* Vrow_hi = Vh + (size_t)(16 + ll) * N_NODES;

    for (int t = 0; t < (N_NODES / 8) / 128; ++t) {
        const int kt = k0 + t * 128;
#pragma unroll
        for (int j = 0; j < 4; ++j) {
            // QK^T for 32-key window (kc = 2j, 2j+1), exp2, pack into P strip
#pragma unroll
            for (int w = 0; w < 2; ++w) {
                const int kc = 2 * j + w;
                bf16x8 kf = *(const bf16x8*)(Kh + (size_t)(kt + kc * 16 + ll) * D_HEAD + lg * 8);
                f32x4 z = {0.f, 0.f, 0.f, 0.f};
                f32x4 d0 = __builtin_amdgcn_mfma_f32_16x16x32_bf16(qf0, kf, z, 0, 0, 0);
                f32x4 d1 = __builtin_amdgcn_mfma_f32_16x16x32_bf16(qf1, kf, z, 0, 0, 0);
#pragma unroll
                for (int r = 0; r < 4; ++r) {
                    float p0 = exp2f(d0[r]); l0[r] += p0;
                    float p1 = exp2f(d1[r]); l1[r] += p1;
                    Pw[(lg * 4 + r) * P2S + w * 16 + ll]      = f2bf(p0);
                    Pw[(16 + lg * 4 + r) * P2S + w * 16 + ll] = f2bf(p1);
                }
            }
            asm volatile("" ::: "memory");   // same-wave DS ordering fence

            // PV for this window
            const int kb = kt + 32 * j + lg * 8;
            bf16x8 va = *(const bf16x8*)(Vrow_lo + kb);
            bf16x8 vb = *(const bf16x8*)(Vrow_hi + kb);
            bf16x8 pf0 = *(const bf16x8*)(Pw + ll * P2S + lg * 8);
            bf16x8 pf1 = *(const bf16x8*)(Pw + (16 + ll) * P2S + lg * 8);
            o00 = __builtin_amdgcn_mfma_f32_16x16x32_bf16(pf0, va, o00, 0, 0, 0);
            o01 = __builtin_amdgcn_mfma_f32_16x16x32_bf16(pf0, vb, o01, 0, 0, 0);
            o10 = __builtin_amdgcn_mfma_f32_16x16x32_bf16(pf1, va, o10, 0, 0, 0);
            o11 = __builtin_amdgcn_mfma_f32_16x16x32_bf16(pf1, vb, o11, 0, 0, 0);
            asm volatile("" ::: "memory");   // keep reads before next window's writes
        }
    }

    // deferred softmax-denominator reduction (16 lanes sharing lg)
#pragma unroll
    for (int r = 0; r < 4; ++r) {
#pragma unroll
        for (int off = 1; off < 16; off <<= 1) {
            l0[r] += __shfl_xor(l0[r], off, 64);
            l1[r] += __shfl_xor(l1[r], off, 64);
        }
    }

    __syncthreads();   // all waves done with P strips; overlay becomes valid

#pragma unroll
    for (int r = 0; r < 4; ++r) {
        Ouns[wv][lg * 4 + r][ll]           = o00[r];
        Ouns[wv][lg * 4 + r][16 + ll]      = o01[r];
        Ouns[wv][16 + lg * 4 + r][ll]      = o10[r];
        Ouns[wv][16 + lg * 4 + r][16 + ll] = o11[r];
    }
    if (ll == 0) {
#pragma unroll
        for (int r = 0; r < 4; ++r) {
            Llp[wv][lg * 4 + r]      = l0[r];
            Llp[wv][16 + lg * 4 + r] = l1[r];
        }
    }
    __syncthreads();

    {
        const int row = tid >> 4, col = tid & 15;
        float L = 0.f, oa = 0.f, obv = 0.f;
#pragma unroll
        for (int w = 0; w < 8; ++w) {
            L   += Llp[w][row];
            oa  += Ouns[w][row][col];
            obv += Ouns[w][row][16 + col];
        }
        float inv = 1.f / L;
        ob[(size_t)(q0 + row) * C_DIM + h * D_HEAD + col]      = f2bf(oa * inv);
        ob[(size_t)(q0 + row) * C_DIM + h * D_HEAD + 16 + col] = f2bf(obv * inv);
    }
}

// ---------------------------------------------------------------------------
// Fused gin2 + aout with deferred-BN3 residual (R17-proven, byte-identical).
// ---------------------------------------------------------------------------
__global__ __launch_bounds__(256, 8) void gemm2x(const unsigned short* __restrict__ A0,
                                                 const unsigned short* __restrict__ W0,
                                                 const float* __restrict__ bias0,
                                                 float* __restrict__ out0,
                                                 float* __restrict__ stats0,
                                                 const unsigned short* __restrict__ A1,
                                                 const unsigned short* __restrict__ W1,
                                                 const float* __restrict__ bias1,
                                                 float* __restrict__ out1,
                                                 float* __restrict__ stats1,
                                                 const float* __restrict__ xprev,
                                                 const float* __restrict__ st3,
                                                 const float* __restrict__ g3p,
                                                 const float* __restrict__ b3p) {
    const int b = blockIdx.x;
    const int which = b >> 9;
    const int bl = b & 511;
    const unsigned short* Abf = which ? A1 : A0;
    const unsigned short* Wbf = which ? W1 : W0;
    const float* bias = which ? bias1 : bias0;
    float* outf  = which ? out1 : out0;
    float* stats = which ? stats1 : stats0;

    const int tid = threadIdx.x;
    const int wv = tid >> 6;
    const int lane = tid & 63, lg = lane >> 4, ll = lane & 15;
    const int rowbase = (bl >> 1) * 16;
    const int colbase = (bl & 1) * 64 + wv * 16;

    const unsigned short* Ap = Abf + (size_t)(rowbase + ll) * 128 + lg * 8;
    const unsigned short* Wp = Wbf + (size_t)(colbase + ll) * 128 + lg * 8;

    f32x4 acc = {0.f, 0.f, 0.f, 0.f};
#pragma unroll
    for (int k = 0; k < 128; k += 32) {
        bf16x8 a = *(const bf16x8*)(Ap + k);
        bf16x8 w = *(const bf16x8*)(Wp + k);
        acc = __builtin_amdgcn_mfma_f32_16x16x32_bf16(a, w, acc, 0, 0, 0);
    }

    const int col = colbase + ll;
    const float bi = bias[col];
    float sc = 1.f, sh = 0.f;
    if (st3) {
        const float inv_n = 1.f / N_NODES;
        float m = st3[col] * inv_n;
        float vv = st3[128 + col] * inv_n - m * m;
        float r = rsqrtf(vv + 1e-5f);
        sc = g3p[col] * r; sh = b3p[col] - m * sc;
    }
    float sv = 0.f, sv2 = 0.f;
#pragma unroll
    for (int r = 0; r < 4; ++r) {
        const int row = rowbase + lg * 4 + r;
        float v = acc[r] + bi + (xprev[(size_t)row * 128 + col] * sc + sh);
        outf[(size_t)row * 128 + col] = v;
        sv += v; sv2 += v * v;
    }
    sv  += __shfl_xor(sv, 16, 64);  sv  += __shfl_xor(sv, 32, 64);
    sv2 += __shfl_xor(sv2, 16, 64); sv2 += __shfl_xor(sv2, 32, 64);
    if (lg == 0) {
        atomicAdd(&stats[col], sv);
        atomicAdd(&stats[128 + col], sv2);
    }
}

// ---------------------------------------------------------------------------
// Fully fused MLP (R16/R17-proven, byte-identical).
// ---------------------------------------------------------------------------
__global__ __launch_bounds__(256) void mlp_fused(const float* __restrict__ g1p,
                                                 const float* __restrict__ a2p,
                                                 const float* __restrict__ st1,
                                                 const float* __restrict__ st2,
                                                 const float* __restrict__ g1v,
                                                 const float* __restrict__ b1v,
                                                 const float* __restrict__ g2v,
                                                 const float* __restrict__ b2v,
                                                 const unsigned short* __restrict__ W1bf,
                                                 const float* __restrict__ bias1,
                                                 const unsigned short* __restrict__ W2bf,
                                                 const float* __restrict__ bias2,
                                                 float* __restrict__ m3out,
                                                 float* __restrict__ stats3) {
    __shared__ float hf[16][132];
    __shared__ __align__(16) unsigned short hs[16 * HS_STRIDE];
    __shared__ __align__(16) unsigned short t2s[16 * T2S];
    __shared__ float scl[4][128];

    const int tid = threadIdx.x;
    const int rowbase = blockIdx.x * 16;
    const float inv_n = 1.f / N_NODES;

    if (tid < 128) {
        const int ch = tid;
        float m1 = st1[ch] * inv_n;
        float v1 = st1[128 + ch] * inv_n - m1 * m1;
        float r1 = rsqrtf(v1 + 1e-5f);
        float sc1 = g1v[ch] * r1;
        scl[0][ch] = sc1;
        scl[1][ch] = b1v[ch] - m1 * sc1;
        float m2 = st2[ch] * inv_n;
        float v2 = st2[128 + ch] * inv_n - m2 * m2;
        float r2 = rsqrtf(v2 + 1e-5f);
        float sc2 = g2v[ch] * r2;
        scl[2][ch] = sc2;
        scl[3][ch] = b2v[ch] - m2 * sc2;
    }
    __syncthreads();

#pragma unroll
    for (int j = tid; j < 512; j += 256) {
        const int r = j >> 5, cq = (j & 31) * 4;
        float4 v1 = *(const float4*)(g1p + (size_t)(rowbase + r) * 128 + cq);
        float4 v2 = *(const float4*)(a2p + (size_t)(rowbase + r) * 128 + cq);
        float h0 = v1.x * scl[0][cq]     + scl[1][cq]     + v2.x * scl[2][cq]     + scl[3][cq];
        float h1 = v1.y * scl[0][cq + 1] + scl[1][cq + 1] + v2.y * scl[2][cq + 1] + scl[3][cq + 1];
        float h2 = v1.z * scl[0][cq + 2] + scl[1][cq + 2] + v2.z * scl[2][cq + 2] + scl[3][cq + 2];
        float h3 = v1.w * scl[0][cq + 3] + scl[1][cq + 3] + v2.w * scl[2][cq + 3] + scl[3][cq + 3];
        hf[r][cq] = h0; hf[r][cq + 1] = h1; hf[r][cq + 2] = h2; hf[r][cq + 3] = h3;
        ushort4 u;
        u.x = f2bf(h0); u.y = f2bf(h1); u.z = f2bf(h2); u.w = f2bf(h3);
        *(ushort4*)(&hs[r * HS_STRIDE + cq]) = u;
    }
    __syncthreads();

    const int wv = tid >> 6;
    const int lane = tid & 63, lg = lane >> 4, ll = lane & 15;

#pragma unroll
    for (int ct = 0; ct < 4; ++ct) {
        const int colbase = wv * 16 + ct * 64;
        const unsigned short* Wp = W1bf + (size_t)(colbase + ll) * 128 + lg * 8;
        f32x4 acc = {0.f, 0.f, 0.f, 0.f};
#pragma unroll
        for (int k = 0; k < 128; k += 32) {
            bf16x8 a = *(const bf16x8*)(&hs[ll * HS_STRIDE + k + lg * 8]);
            bf16x8 w = *(const bf16x8*)(Wp + k);
            acc = __builtin_amdgcn_mfma_f32_16x16x32_bf16(a, w, acc, 0, 0, 0);
        }
        const int col = colbase + ll;
        const float bi = bias1[col];
#pragma unroll
        for (int r = 0; r < 4; ++r) {
            float v = fmaxf(acc[r] + bi, 0.f);
            t2s[(lg * 4 + r) * T2S + col] = f2bf(v);
        }
    }
    __syncthreads();

#pragma unroll
    for (int p = 0; p < 2; ++p) {
        const int colbase = p * 64 + wv * 16;
        const unsigned short* Wp = W2bf + (size_t)(colbase + ll) * 256 + lg * 8;
        f32x4 acc = {0.f, 0.f, 0.f, 0.f};
#pragma unroll
        for (int k = 0; k < 256; k += 32) {
            bf16x8 a = *(const bf16x8*)(&t2s[ll * T2S + k + lg * 8]);
            bf16x8 w = *(const bf16x8*)(Wp + k);
            acc = __builtin_amdgcn_mfma_f32_16x16x32_bf16(a, w, acc, 0, 0, 0);
        }
        const int col = colbase + ll;
        const float bi = bias2[col];
        float sv = 0.f, sv2 = 0.f;
#pragma unroll
        for (int r = 0; r < 4; ++r) {
            const int row = lg * 4 + r;
            float v = acc[r] + bi + hf[row][col];
            m3out[(size_t)(rowbase + row) * 128 + col] = v;
            sv += v; sv2 += v * v;
        }
        sv  += __shfl_xor(sv, 16, 64);  sv  += __shfl_xor(sv, 32, 64);
        sv2 += __shfl_xor(sv2, 16, 64); sv2 += __shfl_xor(sv2, 32, 64);
        if (lg == 0) {
            atomicAdd(&stats3[col], sv);
            atomicAdd(&stats3[128 + col], sv2);
        }
    }
}

// ---------------------------------------------------------------------------
// Fused head MLP with deferred BN3 (R17-proven, byte-identical).
// ---------------------------------------------------------------------------
__global__ __launch_bounds__(256) void head_fused(const float* __restrict__ m3p,
                                                  const float* __restrict__ st3,
                                                  const float* __restrict__ g3p,
                                                  const float* __restrict__ b3p,
                                                  const float* __restrict__ w1,
                                                  const float* __restrict__ b1,
                                                  const float* __restrict__ w2,
                                                  const float* __restrict__ b2,
                                                  const float* __restrict__ w3,
                                                  const float* __restrict__ b3,
                                                  float* __restrict__ out) {
    __shared__ __align__(16) float xs[8][128];
    __shared__ __align__(16) float hs2[8][64];
    __shared__ float scl2[2][128];
    const int tid = threadIdx.x;
    const int n = tid >> 5;
    const int g = tid & 31;
    const int node0 = blockIdx.x * 8;
    const float inv_n = 1.f / N_NODES;

    if (tid < 128) {
        float m = st3[tid] * inv_n;
        float vv = st3[128 + tid] * inv_n - m * m;
        float r = rsqrtf(vv + 1e-5f);
        float sc = g3p[tid] * r;
        scl2[0][tid] = sc;
        scl2[1][tid] = b3p[tid] - m * sc;
    }
    __syncthreads();

    {
        const int e0 = tid * 4;
        const int r = e0 >> 7, c = e0 & 127;
        float4 v = *(const float4*)(m3p + (size_t)(node0 + r) * 128 + c);
        xs[r][c]     = v.x * scl2[0][c]     + scl2[1][c];
        xs[r][c + 1] = v.y * scl2[0][c + 1] + scl2[1][c + 1];
        xs[r][c + 2] = v.z * scl2[0][c + 2] + scl2[1][c + 2];
        xs[r][c + 3] = v.w * scl2[0][c + 3] + scl2[1][c + 3];
    }
    __syncthreads();

    {
        float acc0 = b1[g], acc1 = b1[g + 32];
        const float* wa = w1 + (size_t)g * 128;
        const float* wb = w1 + (size_t)(g + 32) * 128;
#pragma unroll 8
        for (int k = 0; k < 128; k += 4) {
            float4 xv = *(const float4*)(&xs[n][k]);
            float4 va = *(const float4*)(wa + k);
            float4 vb = *(const float4*)(wb + k);
            acc0 += xv.x * va.x + xv.y * va.y + xv.z * va.z + xv.w * va.w;
            acc1 += xv.x * vb.x + xv.y * vb.y + xv.z * vb.z + xv.w * vb.w;
        }
        hs2[n][g]      = fmaxf(acc0, 0.f);
        hs2[n][g + 32] = fmaxf(acc1, 0.f);
    }
    __syncthreads();

    {
        float acc = b2[g];
        const float* wr = w2 + (size_t)g * 64;
#pragma unroll 8
        for (int k = 0; k < 64; k += 4) {
            float4 hv = *(const float4*)(&hs2[n][k]);
            float4 wv = *(const float4*)(wr + k);
            acc += hv.x * wv.x + hv.y * wv.y + hv.z * wv.z + hv.w * wv.w;
        }
        float t = fmaxf(acc, 0.f) * w3[g];
#pragma unroll
        for (int off = 1; off < 32; off <<= 1) t += __shfl_xor(t, off, 64);
        if (g == 0) out[node0 + n] = t + b3[0];
    }
}

// ---------------------------------------------------------------------------
extern "C" void kernel_launch(void* const* d_in, const int* in_sizes, int n_in,
                              void* d_out, int out_size, void* d_ws, size_t ws_size,
                              hipStream_t stream) {
    (void)in_sizes; (void)n_in; (void)out_size; (void)ws_size;
    const float* x_in   = (const float*)d_in[0];
    const int*   ei     = (const int*)d_in[1];
    const float* gin_w1 = (const float*)d_in[2];
    const float* gin_b1 = (const float*)d_in[3];
    const float* gin_w2 = (const float*)d_in[4];
    const float* gin_b2 = (const float*)d_in[5];
    const float* ain_w  = (const float*)d_in[6];
    const float* ain_b  = (const float*)d_in[7];
    const float* aout_w = (const float*)d_in[8];
    const float* aout_b = (const float*)d_in[9];
    const float* n1_g   = (const float*)d_in[10];
    const float* n1_b   = (const float*)d_in[11];
    const float* n2_g   = (const float*)d_in[12];
    const float* n2_b   = (const float*)d_in[13];
    const float* n3_g   = (const float*)d_in[14];
    const float* n3_b   = (const float*)d_in[15];
    const float* mlp_w1 = (const float*)d_in[16];
    const float* mlp_b1 = (const float*)d_in[17];
    const float* mlp_w2 = (const float*)d_in[18];
    const float* mlp_b2 = (const float*)d_in[19];
    const float* h_w1   = (const float*)d_in[20];
    const float* h_b1   = (const float*)d_in[21];
    const float* h_w2   = (const float*)d_in[22];
    const float* h_b2   = (const float*)d_in[23];
    const float* h_w3   = (const float*)d_in[24];
    const float* h_b3   = (const float*)d_in[25];

    float* f = (float*)d_ws;
    float* g1   = f;                   // c0
    float* a2   = f + 1 * (size_t)NC;  // c1 (hsum ushort overlay during steps 1-2)
    float* t1ch = f + 2 * (size_t)NC;  // c2 (t1_bf ushort overlay)
    float* m3   = f + 3 * (size_t)NC;  // c3 (dedicated; persists into next layer)
    unsigned short* R1  = (unsigned short*)(f + 4 * (size_t)NC);  // 3 NCu
    unsigned short* Qb      = R1;
    unsigned short* Kb      = R1 + (size_t)NCu;
    unsigned short* VT      = R1 + 2 * (size_t)NCu;
    unsigned short* R2      = R1 + 3 * (size_t)NCu;  // 1 NCu
    unsigned short* ao_bf   = R2;                    // attn out
    unsigned short* hsum_bf = (unsigned short*)a2;   // gather out (c1 overlay)
    unsigned short* t1_bf   = (unsigned short*)t1ch; // gin1 out (c2 overlay)
    unsigned short* wbf     = R2 + (size_t)NCu;
    float* ssA    = (float*)(wbf + 655360);   // 768 raw sums (parity 0)
    float* ssB    = ssA + 768;                // 768 raw sums (parity 1)
    int* ibase    = (int*)(ssB + 768);
    int* deg      = ibase;
    int* rowstart = ibase + 4096;
    int* cursor   = ibase + 4096 + 4098;
    int* csr_src  = ibase + 4096 + 4098 + 4096;

    const int OG1 = 0, OG2 = 65536, OAI = 131072, OAO = 327680, OM1 = 393216, OM2 = 524288;

    hipMemsetAsync(deg, 0, 4096 * sizeof(int), stream);
    hist_kernel<<<E_EDGES / 256, 256, 0, stream>>>(ei, deg);
    scan_kernel<<<1, 256, 0, stream>>>(deg, rowstart, cursor);
    fill_kernel<<<E_EDGES / 256, 256, 0, stream>>>(ei, cursor, csr_src);
    wcvt<<<320, 256, 0, stream>>>(gin_w1, gin_w2, ain_w, aout_w, mlp_w1, mlp_w2, wbf);

    for (int i = 0; i < L_LAYERS; ++i) {
        const float* xprev = (i == 0) ? x_in : m3;
        const float* st3p  = (i == 0) ? nullptr : ((i & 1) ? ssA : ssB) + 512;
        const float* g3p   = (i == 0) ? nullptr : n3_g + (size_t)(i - 1) * C_DIM;
        const float* b3p   = (i == 0) ? nullptr : n3_b + (size_t)(i - 1) * C_DIM;
        float* ss_cur = (i & 1) ? ssB : ssA;
        const float* gb1 = gin_b1 + (size_t)i * C_DIM;
        const float* gb2 = gin_b2 + (size_t)i * C_DIM;
        const float* aib = ain_b + (size_t)i * 3 * C_DIM;
        const float* aob = aout_b + (size_t)i * C_DIM;
        const float* mb1 = mlp_b1 + (size_t)i * 2 * C_DIM;
        const float* mb2 = mlp_b2 + (size_t)i * C_DIM;

        // 1) fused QKV GEMM + GIN gather, deferred BN3 from (xprev, st3p)
        qkv_gather<<<2560, 256, 0, stream>>>(xprev, st3p, g3p, b3p,
                                             wbf + OAI + (size_t)i * 49152, aib,
                                             Qb, Kb, VT, rowstart, csr_src,
                                             ss_cur, (unsigned int*)hsum_bf);
        // 2) fused attention + gin1 (v5b: session-best configuration)
        attn_gin1<<<768, 512, 0, stream>>>(Qb, Kb, VT, ao_bf,
                                           hsum_bf, wbf + OG1 + (size_t)i * 16384, gb1, t1_bf);
        // 3) fused gin2 + aout (deferred-BN3 residual)
        gemm2x<<<1024, 256, 0, stream>>>(t1_bf, wbf + OG2 + (size_t)i * 16384, gb2, g1, ss_cur,
                                         ao_bf, wbf + OAO + (size_t)i * 16384, aob, a2, ss_cur + 256,
                                         xprev, st3p, g3p, b3p);
        // 4) fully fused MLP -> m3 (c3) + BN3 stats
        mlp_fused<<<256, 256, 0, stream>>>(g1, a2, ss_cur, ss_cur + 256,
                                           n1_g + (size_t)i * C_DIM, n1_b + (size_t)i * C_DIM,
                                           n2_g + (size_t)i * C_DIM, n2_b + (size_t)i * C_DIM,
                                           wbf + OM1 + (size_t)i * 32768, mb1,
                                           wbf + OM2 + (size_t)i * 32768, mb2,
                                           m3, ss_cur + 512);
    }

    // head: x = bn3(m3 of layer 3), scales from ssB+512 (layer-3 parity)
    head_fused<<<N_NODES / 8, 256, 0, stream>>>(m3, ssB + 512,
                                                n3_g + 3 * (size_t)C_DIM, n3_b + 3 * (size_t)C_DIM,
                                                h_w1, h_b1, h_w2, h_b2, h_w3, h_b3,
                                                (float*)d_out);
}

// Round 22
// 349.063 us; speedup vs baseline: 1.2169x; 1.0144x over previous
//
#include <hip/hip_runtime.h>

#define N_NODES 4096
#define C_DIM   128
#define L_LAYERS 4
#define E_EDGES 131072
#define H_HEADS 4
#define D_HEAD  32
#define NC      (N_NODES * C_DIM)
#define NCu     (N_NODES * C_DIM)
#define P2S     40      // attn P window stride (ushorts): 80B rows, 16B-aligned
#define HS_STRIDE 152
#define T2S       264
#define AT_S      136

typedef short bf16x8 __attribute__((ext_vector_type(8)));
typedef float f32x4  __attribute__((ext_vector_type(4)));

__device__ __forceinline__ unsigned short f2bf(float f) {
    unsigned int u = __float_as_uint(f);
    u += 0x7fffu + ((u >> 16) & 1u);
    return (unsigned short)(u >> 16);
}

__device__ __forceinline__ float bf_lo(unsigned int u) { return __uint_as_float(u << 16); }
__device__ __forceinline__ float bf_hi(unsigned int u) { return __uint_as_float(u & 0xffff0000u); }

__device__ __forceinline__ bf16x8 pack8(const float* v) {
    bf16x8 o;
#pragma unroll
    for (int i = 0; i < 8; ++i) o[i] = (short)f2bf(v[i]);
    return o;
}

// ---------------------------------------------------------------------------
// CSR build (once per launch)
// ---------------------------------------------------------------------------
__global__ __launch_bounds__(256) void hist_kernel(const int* __restrict__ ei,
                                                   int* __restrict__ deg) {
    int e = blockIdx.x * 256 + threadIdx.x;
    atomicAdd(&deg[ei[E_EDGES + e]], 1);
}

__global__ __launch_bounds__(256) void scan_kernel(const int* __restrict__ deg,
                                                   int* __restrict__ rowstart,
                                                   int* __restrict__ cursor) {
    __shared__ int ts[256];
    const int tid = threadIdx.x;
    int loc[16];
    int s = 0;
#pragma unroll
    for (int i = 0; i < 16; ++i) { loc[i] = s; s += deg[tid * 16 + i]; }
    ts[tid] = s;
    __syncthreads();
    for (int off = 1; off < 256; off <<= 1) {
        int t = (tid >= off) ? ts[tid - off] : 0;
        __syncthreads();
        if (tid >= off) ts[tid] += t;
        __syncthreads();
    }
    int off0 = ts[tid] - s;
#pragma unroll
    for (int i = 0; i < 16; ++i) {
        int v = off0 + loc[i];
        rowstart[tid * 16 + i] = v;
        cursor[tid * 16 + i] = v;
    }
    if (tid == 255) rowstart[4096] = off0 + s;
}

__global__ __launch_bounds__(256) void fill_kernel(const int* __restrict__ ei,
                                                   int* __restrict__ cursor,
                                                   int* __restrict__ csr_src) {
    int e = blockIdx.x * 256 + threadIdx.x;
    int d = ei[E_EDGES + e];
    int s = ei[e];
    int p = atomicAdd(&cursor[d], 1);
    csr_src[p] = s;
}

// ---------------------------------------------------------------------------
// weight pre-convert fp32 -> bf16
// ---------------------------------------------------------------------------
__global__ __launch_bounds__(256) void wcvt(const float* __restrict__ s0, const float* __restrict__ s1,
                                            const float* __restrict__ s2, const float* __restrict__ s3,
                                            const float* __restrict__ s4, const float* __restrict__ s5,
                                            unsigned short* __restrict__ wbf) {
    int i0 = (blockIdx.x * 256 + threadIdx.x) * 8;
    const float* src; int base;
    if      (i0 < 65536)  { src = s0; base = 0; }
    else if (i0 < 131072) { src = s1; base = 65536; }
    else if (i0 < 327680) { src = s2; base = 131072; }
    else if (i0 < 393216) { src = s3; base = 327680; }
    else if (i0 < 524288) { src = s4; base = 393216; }
    else                  { src = s5; base = 524288; }
    const float* p = src + (i0 - base);
    float t[8];
#pragma unroll
    for (int i = 0; i < 8; ++i) t[i] = p[i];
    *(bf16x8*)(wbf + i0) = pack8(t);
}

// ---------------------------------------------------------------------------
// Fused QKV-GEMM + GIN-gather with deferred BN3 (R17-proven, byte-identical).
// ---------------------------------------------------------------------------
__global__ __launch_bounds__(256, 8) void qkv_gather(const float* __restrict__ xprev,
                                                     const float* __restrict__ st3,
                                                     const float* __restrict__ g3p,
                                                     const float* __restrict__ b3p,
                                                     const unsigned short* __restrict__ Wbf,
                                                     const float* __restrict__ bias,
                                                     unsigned short* __restrict__ Qb,
                                                     unsigned short* __restrict__ Kb,
                                                     unsigned short* __restrict__ VT,
                                                     const int* __restrict__ rowstart,
                                                     const int* __restrict__ csr_src,
                                                     float* __restrict__ ssz,
                                                     unsigned int* __restrict__ hsum) {
    __shared__ float scl2[2][128];
    __shared__ __align__(16) unsigned short at[16 * AT_S];

    const int b = blockIdx.x;
    const int tid = threadIdx.x;
    const float inv_n = 1.f / N_NODES;

    if (b < 1536) {
        const int ct = b % 6, rt = b / 6;
        const int rowbase = rt * 16;

        if (tid < 128) {
            float sc = 1.f, sh = 0.f;
            if (st3) {
                float m = st3[tid] * inv_n;
                float vv = st3[128 + tid] * inv_n - m * m;
                float r = rsqrtf(vv + 1e-5f);
                sc = g3p[tid] * r;
                sh = b3p[tid] - m * sc;
            }
            scl2[0][tid] = sc; scl2[1][tid] = sh;
        }
        __syncthreads();

        {
            const int e0 = tid * 8;
            const int r = e0 >> 7, c = e0 & 127;
            const float* xp = xprev + (size_t)(rowbase + r) * 128 + c;
            float t[8];
#pragma unroll
            for (int i = 0; i < 8; ++i) t[i] = xp[i] * scl2[0][c + i] + scl2[1][c + i];
            *(bf16x8*)(&at[r * AT_S + c]) = pack8(t);
        }
        __syncthreads();

        const int wv = tid >> 6;
        const int lane = tid & 63, lg = lane >> 4, ll = lane & 15;
        const int colbase = ct * 64 + wv * 16;
        const unsigned short* Wp = Wbf + (size_t)(colbase + ll) * 128 + lg * 8;

        f32x4 acc = {0.f, 0.f, 0.f, 0.f};
#pragma unroll
        for (int k = 0; k < 128; k += 32) {
            bf16x8 a = *(const bf16x8*)(&at[ll * AT_S + k + lg * 8]);
            bf16x8 w = *(const bf16x8*)(Wp + k);
            acc = __builtin_amdgcn_mfma_f32_16x16x32_bf16(a, w, acc, 0, 0, 0);
        }

        const float qsc = 0.25506973f;  // (1/sqrt(32)) * log2(e)
        const int col = colbase + ll;
        const float bi = bias[col];
#pragma unroll
        for (int r = 0; r < 4; ++r) {
            const int row = rowbase + lg * 4 + r;
            float v = acc[r] + bi;
            if (col < 128) {
                int hh = col >> 5, d = col & 31;
                Qb[((size_t)hh * N_NODES + row) * D_HEAD + d] = f2bf(v * qsc);
            } else if (col < 256) {
                int c2 = col - 128, hh = c2 >> 5, d = c2 & 31;
                Kb[((size_t)hh * N_NODES + row) * D_HEAD + d] = f2bf(v);
            } else {
                int c2 = col - 256, hh = c2 >> 5, d = c2 & 31;
                VT[((size_t)hh * D_HEAD + d) * N_NODES + row] = f2bf(v);
            }
        }
    } else {
        if (b == 1536) {
            ssz[tid] = 0.f; ssz[256 + tid] = 0.f; ssz[512 + tid] = 0.f;
        }
        const int node = (b - 1536) * 4 + (tid >> 6);
        const int lane = tid & 63;
        const int ch0 = lane * 2, ch1 = ch0 + 1;
        float sc0 = 1.f, sh0 = 0.f, sc1 = 1.f, sh1 = 0.f;
        if (st3) {
            float m0 = st3[ch0] * inv_n;
            float v0 = st3[128 + ch0] * inv_n - m0 * m0;
            float r0 = rsqrtf(v0 + 1e-5f);
            sc0 = g3p[ch0] * r0; sh0 = b3p[ch0] - m0 * sc0;
            float m1 = st3[ch1] * inv_n;
            float v1 = st3[128 + ch1] * inv_n - m1 * m1;
            float r1 = rsqrtf(v1 + 1e-5f);
            sc1 = g3p[ch1] * r1; sh1 = b3p[ch1] - m1 * sc1;
        }
        const int beg = rowstart[node], end = rowstart[node + 1];
        float2 sv = *(const float2*)(xprev + (size_t)node * 128 + ch0);
        float ax = sv.x * sc0 + sh0, ay = sv.y * sc1 + sh1;
        float bx = 0.f, by = 0.f;
        int e = beg;
        for (; e + 4 <= end; e += 4) {
            int s0 = csr_src[e], s1 = csr_src[e + 1], s2 = csr_src[e + 2], s3 = csr_src[e + 3];
            float2 v0 = *(const float2*)(xprev + (size_t)s0 * 128 + ch0);
            float2 v1 = *(const float2*)(xprev + (size_t)s1 * 128 + ch0);
            float2 v2 = *(const float2*)(xprev + (size_t)s2 * 128 + ch0);
            float2 v3 = *(const float2*)(xprev + (size_t)s3 * 128 + ch0);
            ax += (v0.x * sc0 + sh0) + (v1.x * sc0 + sh0);
            ay += (v0.y * sc1 + sh1) + (v1.y * sc1 + sh1);
            bx += (v2.x * sc0 + sh0) + (v3.x * sc0 + sh0);
            by += (v2.y * sc1 + sh1) + (v3.y * sc1 + sh1);
        }
        for (; e < end; ++e) {
            float2 v0 = *(const float2*)(xprev + (size_t)csr_src[e] * 128 + ch0);
            ax += v0.x * sc0 + sh0; ay += v0.y * sc1 + sh1;
        }
        float ox = ax + bx, oy = ay + by;
        hsum[(size_t)node * 64 + lane] = (unsigned int)f2bf(ox) | ((unsigned int)f2bf(oy) << 16);
    }
}

// ---------------------------------------------------------------------------
// Fused attention + GIN-MLP-1, v5c = R19/R21 session-best + T5 s_setprio
// around each window body (scheduler hint only; math byte-identical).
// m191: setprio isolated on attn = +4-7%. Waves here are barrier-free and
// drift to different phases -> role diversity exists for the arbiter.
// ---------------------------------------------------------------------------
__global__ __launch_bounds__(512, 4) void attn_gin1(const unsigned short* __restrict__ Qb,
                                                    const unsigned short* __restrict__ Kb,
                                                    const unsigned short* __restrict__ VT,
                                                    unsigned short* __restrict__ ob,
                                                    const unsigned short* __restrict__ hsum,
                                                    const unsigned short* __restrict__ W1,
                                                    const float* __restrict__ bias1,
                                                    unsigned short* __restrict__ t1out) {
    __shared__ __align__(16) float Ouns[8][32][33];   // 33792 B (P strips alias this)
    __shared__ float Llp[8][32];                      //  1024 B

    const int b   = blockIdx.x;
    const int tid = threadIdx.x;
    const int wv  = tid >> 6;
    const int lane = tid & 63;
    const int lg  = lane >> 4;
    const int ll  = lane & 15;

    if (b >= 512) {
        // ---- gin1 GEMM branch ----
        const int rowbase = (b - 512) * 16;
        const int colbase = wv * 16;
        const unsigned short* Ap = hsum + (size_t)(rowbase + ll) * 128 + lg * 8;
        const unsigned short* Wp = W1 + (size_t)(colbase + ll) * 128 + lg * 8;
        f32x4 acc = {0.f, 0.f, 0.f, 0.f};
#pragma unroll
        for (int k = 0; k < 128; k += 32) {
            bf16x8 a = *(const bf16x8*)(Ap + k);
            bf16x8 w = *(const bf16x8*)(Wp + k);
            acc = __builtin_amdgcn_mfma_f32_16x16x32_bf16(a, w, acc, 0, 0, 0);
        }
        const int col = colbase + ll;
        const float bi = bias1[col];
#pragma unroll
        for (int r = 0; r < 4; ++r) {
            const int row = rowbase + lg * 4 + r;
            float v = fmaxf(acc[r] + bi, 0.f);
            t1out[(size_t)row * 128 + col] = f2bf(v);
        }
        return;
    }

    // ---- attention branch ----
    const int h   = b >> 7;
    const int q0  = (b & 127) * 32;

    const unsigned short* Qh = Qb + ((size_t)h * N_NODES + q0) * D_HEAD;
    const unsigned short* Kh = Kb + (size_t)h * N_NODES * D_HEAD;
    const unsigned short* Vh = VT + (size_t)h * D_HEAD * N_NODES;

    bf16x8 qf0 = *(const bf16x8*)(Qh + ll * D_HEAD + lg * 8);
    bf16x8 qf1 = *(const bf16x8*)(Qh + (16 + ll) * D_HEAD + lg * 8);

    f32x4 o00 = {0.f,0.f,0.f,0.f}, o01 = {0.f,0.f,0.f,0.f};
    f32x4 o10 = {0.f,0.f,0.f,0.f}, o11 = {0.f,0.f,0.f,0.f};
    float l0[4] = {0.f,0.f,0.f,0.f}, l1[4] = {0.f,0.f,0.f,0.f};

    // per-wave 32x(32+8) bf16 P strip aliased into the Ouns storage
    unsigned short* Pw = (unsigned short*)(void*)Ouns + wv * (32 * P2S);
    const int k0 = wv * (N_NODES / 8);
    const unsigned short* Vrow_lo = Vh + (size_t)ll * N_NODES;
    const unsigned short* Vrow_hi = Vh + (size_t)(16 + ll) * N_NODES;

    for (int t = 0; t < (N_NODES / 8) / 128; ++t) {
        const int kt = k0 + t * 128;
#pragma unroll
        for (int j = 0; j < 4; ++j) {
            __builtin_amdgcn_s_setprio(1);
            // QK^T for 32-key window (kc = 2j, 2j+1), exp2, pack into P strip
#pragma unroll
            for (int w = 0; w < 2; ++w) {
                const int kc = 2 * j + w;
                bf16x8 kf = *(const bf16x8*)(Kh + (size_t)(kt + kc * 16 + ll) * D_HEAD + lg * 8);
                f32x4 z = {0.f, 0.f, 0.f, 0.f};
                f32x4 d0 = __builtin_amdgcn_mfma_f32_16x16x32_bf16(qf0, kf, z, 0, 0, 0);
                f32x4 d1 = __builtin_amdgcn_mfma_f32_16x16x32_bf16(qf1, kf, z, 0, 0, 0);
#pragma unroll
                for (int r = 0; r < 4; ++r) {
                    float p0 = exp2f(d0[r]); l0[r] += p0;
                    float p1 = exp2f(d1[r]); l1[r] += p1;
                    Pw[(lg * 4 + r) * P2S + w * 16 + ll]      = f2bf(p0);
                    Pw[(16 + lg * 4 + r) * P2S + w * 16 + ll] = f2bf(p1);
                }
            }
            asm volatile("" ::: "memory");   // same-wave DS ordering fence

            // PV for this window
            const int kb = kt + 32 * j + lg * 8;
            bf16x8 va = *(const bf16x8*)(Vrow_lo + kb);
            bf16x8 vb = *(const bf16x8*)(Vrow_hi + kb);
            bf16x8 pf0 = *(const bf16x8*)(Pw + ll * P2S + lg * 8);
            bf16x8 pf1 = *(const bf16x8*)(Pw + (16 + ll) * P2S + lg * 8);
            o00 = __builtin_amdgcn_mfma_f32_16x16x32_bf16(pf0, va, o00, 0, 0, 0);
            o01 = __builtin_amdgcn_mfma_f32_16x16x32_bf16(pf0, vb, o01, 0, 0, 0);
            o10 = __builtin_amdgcn_mfma_f32_16x16x32_bf16(pf1, va, o10, 0, 0, 0);
            o11 = __builtin_amdgcn_mfma_f32_16x16x32_bf16(pf1, vb, o11, 0, 0, 0);
            __builtin_amdgcn_s_setprio(0);
            asm volatile("" ::: "memory");   // keep reads before next window's writes
        }
    }

    // deferred softmax-denominator reduction (16 lanes sharing lg)
#pragma unroll
    for (int r = 0; r < 4; ++r) {
#pragma unroll
        for (int off = 1; off < 16; off <<= 1) {
            l0[r] += __shfl_xor(l0[r], off, 64);
            l1[r] += __shfl_xor(l1[r], off, 64);
        }
    }

    __syncthreads();   // all waves done with P strips; overlay becomes valid

#pragma unroll
    for (int r = 0; r < 4; ++r) {
        Ouns[wv][lg * 4 + r][ll]           = o00[r];
        Ouns[wv][lg * 4 + r][16 + ll]      = o01[r];
        Ouns[wv][16 + lg * 4 + r][ll]      = o10[r];
        Ouns[wv][16 + lg * 4 + r][16 + ll] = o11[r];
    }
    if (ll == 0) {
#pragma unroll
        for (int r = 0; r < 4; ++r) {
            Llp[wv][lg * 4 + r]      = l0[r];
            Llp[wv][16 + lg * 4 + r] = l1[r];
        }
    }
    __syncthreads();

    {
        const int row = tid >> 4, col = tid & 15;
        float L = 0.f, oa = 0.f, obv = 0.f;
#pragma unroll
        for (int w = 0; w < 8; ++w) {
            L   += Llp[w][row];
            oa  += Ouns[w][row][col];
            obv += Ouns[w][row][16 + col];
        }
        float inv = 1.f / L;
        ob[(size_t)(q0 + row) * C_DIM + h * D_HEAD + col]      = f2bf(oa * inv);
        ob[(size_t)(q0 + row) * C_DIM + h * D_HEAD + 16 + col] = f2bf(obv * inv);
    }
}

// ---------------------------------------------------------------------------
// Fused gin2 + aout with deferred-BN3 residual (R17-proven, byte-identical).
// ---------------------------------------------------------------------------
__global__ __launch_bounds__(256, 8) void gemm2x(const unsigned short* __restrict__ A0,
                                                 const unsigned short* __restrict__ W0,
                                                 const float* __restrict__ bias0,
                                                 float* __restrict__ out0,
                                                 float* __restrict__ stats0,
                                                 const unsigned short* __restrict__ A1,
                                                 const unsigned short* __restrict__ W1,
                                                 const float* __restrict__ bias1,
                                                 float* __restrict__ out1,
                                                 float* __restrict__ stats1,
                                                 const float* __restrict__ xprev,
                                                 const float* __restrict__ st3,
                                                 const float* __restrict__ g3p,
                                                 const float* __restrict__ b3p) {
    const int b = blockIdx.x;
    const int which = b >> 9;
    const int bl = b & 511;
    const unsigned short* Abf = which ? A1 : A0;
    const unsigned short* Wbf = which ? W1 : W0;
    const float* bias = which ? bias1 : bias0;
    float* outf  = which ? out1 : out0;
    float* stats = which ? stats1 : stats0;

    const int tid = threadIdx.x;
    const int wv = tid >> 6;
    const int lane = tid & 63, lg = lane >> 4, ll = lane & 15;
    const int rowbase = (bl >> 1) * 16;
    const int colbase = (bl & 1) * 64 + wv * 16;

    const unsigned short* Ap = Abf + (size_t)(rowbase + ll) * 128 + lg * 8;
    const unsigned short* Wp = Wbf + (size_t)(colbase + ll) * 128 + lg * 8;

    f32x4 acc = {0.f, 0.f, 0.f, 0.f};
#pragma unroll
    for (int k = 0; k < 128; k += 32) {
        bf16x8 a = *(const bf16x8*)(Ap + k);
        bf16x8 w = *(const bf16x8*)(Wp + k);
        acc = __builtin_amdgcn_mfma_f32_16x16x32_bf16(a, w, acc, 0, 0, 0);
    }

    const int col = colbase + ll;
    const float bi = bias[col];
    float sc = 1.f, sh = 0.f;
    if (st3) {
        const float inv_n = 1.f / N_NODES;
        float m = st3[col] * inv_n;
        float vv = st3[128 + col] * inv_n - m * m;
        float r = rsqrtf(vv + 1e-5f);
        sc = g3p[col] * r; sh = b3p[col] - m * sc;
    }
    float sv = 0.f, sv2 = 0.f;
#pragma unroll
    for (int r = 0; r < 4; ++r) {
        const int row = rowbase + lg * 4 + r;
        float v = acc[r] + bi + (xprev[(size_t)row * 128 + col] * sc + sh);
        outf[(size_t)row * 128 + col] = v;
        sv += v; sv2 += v * v;
    }
    sv  += __shfl_xor(sv, 16, 64);  sv  += __shfl_xor(sv, 32, 64);
    sv2 += __shfl_xor(sv2, 16, 64); sv2 += __shfl_xor(sv2, 32, 64);
    if (lg == 0) {
        atomicAdd(&stats[col], sv);
        atomicAdd(&stats[128 + col], sv2);
    }
}

// ---------------------------------------------------------------------------
// Fully fused MLP (R16/R17-proven, byte-identical).
// ---------------------------------------------------------------------------
__global__ __launch_bounds__(256) void mlp_fused(const float* __restrict__ g1p,
                                                 const float* __restrict__ a2p,
                                                 const float* __restrict__ st1,
                                                 const float* __restrict__ st2,
                                                 const float* __restrict__ g1v,
                                                 const float* __restrict__ b1v,
                                                 const float* __restrict__ g2v,
                                                 const float* __restrict__ b2v,
                                                 const unsigned short* __restrict__ W1bf,
                                                 const float* __restrict__ bias1,
                                                 const unsigned short* __restrict__ W2bf,
                                                 const float* __restrict__ bias2,
                                                 float* __restrict__ m3out,
                                                 float* __restrict__ stats3) {
    __shared__ float hf[16][132];
    __shared__ __align__(16) unsigned short hs[16 * HS_STRIDE];
    __shared__ __align__(16) unsigned short t2s[16 * T2S];
    __shared__ float scl[4][128];

    const int tid = threadIdx.x;
    const int rowbase = blockIdx.x * 16;
    const float inv_n = 1.f / N_NODES;

    if (tid < 128) {
        const int ch = tid;
        float m1 = st1[ch] * inv_n;
        float v1 = st1[128 + ch] * inv_n - m1 * m1;
        float r1 = rsqrtf(v1 + 1e-5f);
        float sc1 = g1v[ch] * r1;
        scl[0][ch] = sc1;
        scl[1][ch] = b1v[ch] - m1 * sc1;
        float m2 = st2[ch] * inv_n;
        float v2 = st2[128 + ch] * inv_n - m2 * m2;
        float r2 = rsqrtf(v2 + 1e-5f);
        float sc2 = g2v[ch] * r2;
        scl[2][ch] = sc2;
        scl[3][ch] = b2v[ch] - m2 * sc2;
    }
    __syncthreads();

#pragma unroll
    for (int j = tid; j < 512; j += 256) {
        const int r = j >> 5, cq = (j & 31) * 4;
        float4 v1 = *(const float4*)(g1p + (size_t)(rowbase + r) * 128 + cq);
        float4 v2 = *(const float4*)(a2p + (size_t)(rowbase + r) * 128 + cq);
        float h0 = v1.x * scl[0][cq]     + scl[1][cq]     + v2.x * scl[2][cq]     + scl[3][cq];
        float h1 = v1.y * scl[0][cq + 1] + scl[1][cq + 1] + v2.y * scl[2][cq + 1] + scl[3][cq + 1];
        float h2 = v1.z * scl[0][cq + 2] + scl[1][cq + 2] + v2.z * scl[2][cq + 2] + scl[3][cq + 2];
        float h3 = v1.w * scl[0][cq + 3] + scl[1][cq + 3] + v2.w * scl[2][cq + 3] + scl[3][cq + 3];
        hf[r][cq] = h0; hf[r][cq + 1] = h1; hf[r][cq + 2] = h2; hf[r][cq + 3] = h3;
        ushort4 u;
        u.x = f2bf(h0); u.y = f2bf(h1); u.z = f2bf(h2); u.w = f2bf(h3);
        *(ushort4*)(&hs[r * HS_STRIDE + cq]) = u;
    }
    __syncthreads();

    const int wv = tid >> 6;
    const int lane = tid & 63, lg = lane >> 4, ll = lane & 15;

#pragma unroll
    for (int ct = 0; ct < 4; ++ct) {
        const int colbase = wv * 16 + ct * 64;
        const unsigned short* Wp = W1bf + (size_t)(colbase + ll) * 128 + lg * 8;
        f32x4 acc = {0.f, 0.f, 0.f, 0.f};
#pragma unroll
        for (int k = 0; k < 128; k += 32) {
            bf16x8 a = *(const bf16x8*)(&hs[ll * HS_STRIDE + k + lg * 8]);
            bf16x8 w = *(const bf16x8*)(Wp + k);
            acc = __builtin_amdgcn_mfma_f32_16x16x32_bf16(a, w, acc, 0, 0, 0);
        }
        const int col = colbase + ll;
        const float bi = bias1[col];
#pragma unroll
        for (int r = 0; r < 4; ++r) {
            float v = fmaxf(acc[r] + bi, 0.f);
            t2s[(lg * 4 + r) * T2S + col] = f2bf(v);
        }
    }
    __syncthreads();

#pragma unroll
    for (int p = 0; p < 2; ++p) {
        const int colbase = p * 64 + wv * 16;
        const unsigned short* Wp = W2bf + (size_t)(colbase + ll) * 256 + lg * 8;
        f32x4 acc = {0.f, 0.f, 0.f, 0.f};
#pragma unroll
        for (int k = 0; k < 256; k += 32) {
            bf16x8 a = *(const bf16x8*)(&t2s[ll * T2S + k + lg * 8]);
            bf16x8 w = *(const bf16x8*)(Wp + k);
            acc = __builtin_amdgcn_mfma_f32_16x16x32_bf16(a, w, acc, 0, 0, 0);
        }
        const int col = colbase + ll;
        const float bi = bias2[col];
        float sv = 0.f, sv2 = 0.f;
#pragma unroll
        for (int r = 0; r < 4; ++r) {
            const int row = lg * 4 + r;
            float v = acc[r] + bi + hf[row][col];
            m3out[(size_t)(rowbase + row) * 128 + col] = v;
            sv += v; sv2 += v * v;
        }
        sv  += __shfl_xor(sv, 16, 64);  sv  += __shfl_xor(sv, 32, 64);
        sv2 += __shfl_xor(sv2, 16, 64); sv2 += __shfl_xor(sv2, 32, 64);
        if (lg == 0) {
            atomicAdd(&stats3[col], sv);
            atomicAdd(&stats3[128 + col], sv2);
        }
    }
}

// ---------------------------------------------------------------------------
// Fused head MLP with deferred BN3 (R17-proven, byte-identical).
// ---------------------------------------------------------------------------
__global__ __launch_bounds__(256) void head_fused(const float* __restrict__ m3p,
                                                  const float* __restrict__ st3,
                                                  const float* __restrict__ g3p,
                                                  const float* __restrict__ b3p,
                                                  const float* __restrict__ w1,
                                                  const float* __restrict__ b1,
                                                  const float* __restrict__ w2,
                                                  const float* __restrict__ b2,
                                                  const float* __restrict__ w3,
                                                  const float* __restrict__ b3,
                                                  float* __restrict__ out) {
    __shared__ __align__(16) float xs[8][128];
    __shared__ __align__(16) float hs2[8][64];
    __shared__ float scl2[2][128];
    const int tid = threadIdx.x;
    const int n = tid >> 5;
    const int g = tid & 31;
    const int node0 = blockIdx.x * 8;
    const float inv_n = 1.f / N_NODES;

    if (tid < 128) {
        float m = st3[tid] * inv_n;
        float vv = st3[128 + tid] * inv_n - m * m;
        float r = rsqrtf(vv + 1e-5f);
        float sc = g3p[tid] * r;
        scl2[0][tid] = sc;
        scl2[1][tid] = b3p[tid] - m * sc;
    }
    __syncthreads();

    {
        const int e0 = tid * 4;
        const int r = e0 >> 7, c = e0 & 127;
        float4 v = *(const float4*)(m3p + (size_t)(node0 + r) * 128 + c);
        xs[r][c]     = v.x * scl2[0][c]     + scl2[1][c];
        xs[r][c + 1] = v.y * scl2[0][c + 1] + scl2[1][c + 1];
        xs[r][c + 2] = v.z * scl2[0][c + 2] + scl2[1][c + 2];
        xs[r][c + 3] = v.w * scl2[0][c + 3] + scl2[1][c + 3];
    }
    __syncthreads();

    {
        float acc0 = b1[g], acc1 = b1[g + 32];
        const float* wa = w1 + (size_t)g * 128;
        const float* wb = w1 + (size_t)(g + 32) * 128;
#pragma unroll 8
        for (int k = 0; k < 128; k += 4) {
            float4 xv = *(const float4*)(&xs[n][k]);
            float4 va = *(const float4*)(wa + k);
            float4 vb = *(const float4*)(wb + k);
            acc0 += xv.x * va.x + xv.y * va.y + xv.z * va.z + xv.w * va.w;
            acc1 += xv.x * vb.x + xv.y * vb.y + xv.z * vb.z + xv.w * vb.w;
        }
        hs2[n][g]      = fmaxf(acc0, 0.f);
        hs2[n][g + 32] = fmaxf(acc1, 0.f);
    }
    __syncthreads();

    {
        float acc = b2[g];
        const float* wr = w2 + (size_t)g * 64;
#pragma unroll 8
        for (int k = 0; k < 64; k += 4) {
            float4 hv = *(const float4*)(&hs2[n][k]);
            float4 wv = *(const float4*)(wr + k);
            acc += hv.x * wv.x + hv.y * wv.y + hv.z * wv.z + hv.w * wv.w;
        }
        float t = fmaxf(acc, 0.f) * w3[g];
#pragma unroll
        for (int off = 1; off < 32; off <<= 1) t += __shfl_xor(t, off, 64);
        if (g == 0) out[node0 + n] = t + b3[0];
    }
}

// ---------------------------------------------------------------------------
extern "C" void kernel_launch(void* const* d_in, const int* in_sizes, int n_in,
                              void* d_out, int out_size, void* d_ws, size_t ws_size,
                              hipStream_t stream) {
    (void)in_sizes; (void)n_in; (void)out_size; (void)ws_size;
    const float* x_in   = (const float*)d_in[0];
    const int*   ei     = (const int*)d_in[1];
    const float* gin_w1 = (const float*)d_in[2];
    const float* gin_b1 = (const float*)d_in[3];
    const float* gin_w2 = (const float*)d_in[4];
    const float* gin_b2 = (const float*)d_in[5];
    const float* ain_w  = (const float*)d_in[6];
    const float* ain_b  = (const float*)d_in[7];
    const float* aout_w = (const float*)d_in[8];
    const float* aout_b = (const float*)d_in[9];
    const float* n1_g   = (const float*)d_in[10];
    const float* n1_b   = (const float*)d_in[11];
    const float* n2_g   = (const float*)d_in[12];
    const float* n2_b   = (const float*)d_in[13];
    const float* n3_g   = (const float*)d_in[14];
    const float* n3_b   = (const float*)d_in[15];
    const float* mlp_w1 = (const float*)d_in[16];
    const float* mlp_b1 = (const float*)d_in[17];
    const float* mlp_w2 = (const float*)d_in[18];
    const float* mlp_b2 = (const float*)d_in[19];
    const float* h_w1   = (const float*)d_in[20];
    const float* h_b1   = (const float*)d_in[21];
    const float* h_w2   = (const float*)d_in[22];
    const float* h_b2   = (const float*)d_in[23];
    const float* h_w3   = (const float*)d_in[24];
    const float* h_b3   = (const float*)d_in[25];

    float* f = (float*)d_ws;
    float* g1   = f;                   // c0
    float* a2   = f + 1 * (size_t)NC;  // c1 (hsum ushort overlay during steps 1-2)
    float* t1ch = f + 2 * (size_t)NC;  // c2 (t1_bf ushort overlay)
    float* m3   = f + 3 * (size_t)NC;  // c3 (dedicated; persists into next layer)
    unsigned short* R1  = (unsigned short*)(f + 4 * (size_t)NC);  // 3 NCu
    unsigned short* Qb      = R1;
    unsigned short* Kb      = R1 + (size_t)NCu;
    unsigned short* VT      = R1 + 2 * (size_t)NCu;
    unsigned short* R2      = R1 + 3 * (size_t)NCu;  // 1 NCu
    unsigned short* ao_bf   = R2;                    // attn out
    unsigned short* hsum_bf = (unsigned short*)a2;   // gather out (c1 overlay)
    unsigned short* t1_bf   = (unsigned short*)t1ch; // gin1 out (c2 overlay)
    unsigned short* wbf     = R2 + (size_t)NCu;
    float* ssA    = (float*)(wbf + 655360);   // 768 raw sums (parity 0)
    float* ssB    = ssA + 768;                // 768 raw sums (parity 1)
    int* ibase    = (int*)(ssB + 768);
    int* deg      = ibase;
    int* rowstart = ibase + 4096;
    int* cursor   = ibase + 4096 + 4098;
    int* csr_src  = ibase + 4096 + 4098 + 4096;

    const int OG1 = 0, OG2 = 65536, OAI = 131072, OAO = 327680, OM1 = 393216, OM2 = 524288;

    hipMemsetAsync(deg, 0, 4096 * sizeof(int), stream);
    hist_kernel<<<E_EDGES / 256, 256, 0, stream>>>(ei, deg);
    scan_kernel<<<1, 256, 0, stream>>>(deg, rowstart, cursor);
    fill_kernel<<<E_EDGES / 256, 256, 0, stream>>>(ei, cursor, csr_src);
    wcvt<<<320, 256, 0, stream>>>(gin_w1, gin_w2, ain_w, aout_w, mlp_w1, mlp_w2, wbf);

    for (int i = 0; i < L_LAYERS; ++i) {
        const float* xprev = (i == 0) ? x_in : m3;
        const float* st3p  = (i == 0) ? nullptr : ((i & 1) ? ssA : ssB) + 512;
        const float* g3p   = (i == 0) ? nullptr : n3_g + (size_t)(i - 1) * C_DIM;
        const float* b3p   = (i == 0) ? nullptr : n3_b + (size_t)(i - 1) * C_DIM;
        float* ss_cur = (i & 1) ? ssB : ssA;
        const float* gb1 = gin_b1 + (size_t)i * C_DIM;
        const float* gb2 = gin_b2 + (size_t)i * C_DIM;
        const float* aib = ain_b + (size_t)i * 3 * C_DIM;
        const float* aob = aout_b + (size_t)i * C_DIM;
        const float* mb1 = mlp_b1 + (size_t)i * 2 * C_DIM;
        const float* mb2 = mlp_b2 + (size_t)i * C_DIM;

        // 1) fused QKV GEMM + GIN gather, deferred BN3 from (xprev, st3p)
        qkv_gather<<<2560, 256, 0, stream>>>(xprev, st3p, g3p, b3p,
                                             wbf + OAI + (size_t)i * 49152, aib,
                                             Qb, Kb, VT, rowstart, csr_src,
                                             ss_cur, (unsigned int*)hsum_bf);
        // 2) fused attention + gin1 (v5c: + s_setprio)
        attn_gin1<<<768, 512, 0, stream>>>(Qb, Kb, VT, ao_bf,
                                           hsum_bf, wbf + OG1 + (size_t)i * 16384, gb1, t1_bf);
        // 3) fused gin2 + aout (deferred-BN3 residual)
        gemm2x<<<1024, 256, 0, stream>>>(t1_bf, wbf + OG2 + (size_t)i * 16384, gb2, g1, ss_cur,
                                         ao_bf, wbf + OAO + (size_t)i * 16384, aob, a2, ss_cur + 256,
                                         xprev, st3p, g3p, b3p);
        // 4) fully fused MLP -> m3 (c3) + BN3 stats
        mlp_fused<<<256, 256, 0, stream>>>(g1, a2, ss_cur, ss_cur + 256,
                                           n1_g + (size_t)i * C_DIM, n1_b + (size_t)i * C_DIM,
                                           n2_g + (size_t)i * C_DIM, n2_b + (size_t)i * C_DIM,
                                           wbf + OM1 + (size_t)i * 32768, mb1,
                                           wbf + OM2 + (size_t)i * 32768, mb2,
                                           m3, ss_cur + 512);
    }

    // head: x = bn3(m3 of layer 3), scales from ssB+512 (layer-3 parity)
    head_fused<<<N_NODES / 8, 256, 0, stream>>>(m3, ssB + 512,
                                                n3_g + 3 * (size_t)C_DIM, n3_b + 3 * (size_t)C_DIM,
                                                h_w1, h_b1, h_w2, h_b2, h_w3, h_b3,
                                                (float*)d_out);
}